// Round 9
// baseline (3972.637 us; speedup 1.0000x reference)
//
#include <hip/hip_runtime.h>

#define LEAKY 0.2f
#define BN_EPS 1e-5f
#define BCHUNK 8192

typedef __bf16 v8bf __attribute__((ext_vector_type(8)));
typedef float v16f __attribute__((ext_vector_type(16)));
typedef float v2f __attribute__((ext_vector_type(2)));

// ---------- wave helpers (wave64) ----------
__device__ __forceinline__ float wsum(float v) {
#pragma unroll
  for (int o = 32; o > 0; o >>= 1) v += __shfl_xor(v, o, 64);
  return v;
}

// packed-bf16: dword holds feat2j (low16) and feat2j+1 (high16)
__device__ __forceinline__ float blo(unsigned u) { return __uint_as_float(u << 16); }
__device__ __forceinline__ float bhi(unsigned u) { return __uint_as_float(u & 0xffff0000u); }
__device__ __forceinline__ v2f bpair(unsigned u) {
  v2f r; r.x = __uint_as_float(u << 16); r.y = __uint_as_float(u & 0xffff0000u); return r;
}
__device__ __forceinline__ unsigned pack_bf16(float a, float b) {
  unsigned ua = __float_as_uint(a), ub = __float_as_uint(b);
  ua = (ua + 0x7fffu + ((ua >> 16) & 1u)) >> 16;
  ub = (ub + 0x7fffu + ((ub >> 16) & 1u)) >> 16;
  return ua | (ub << 16);
}
__device__ __forceinline__ unsigned short bf16of(float a) {
  unsigned ua = __float_as_uint(a);
  return (unsigned short)((ua + 0x7fffu + ((ua >> 16) & 1u)) >> 16);
}

// edge_index may be int64 (reference dtype) or int32 (JAX x64 disabled).
__device__ __forceinline__ int edge_at(const void* ei, int is64, long long i) {
  return is64 ? (int)((const long long*)ei)[i] : ((const int*)ei)[i];
}

// ---------- CSR build: two-level counting sort (write-local) ----------
__global__ __launch_bounds__(256) void k_binA(const void* ei, int N, int E, int M,
                                              int nb, int nblk, int* counts) {
  __shared__ int hist[1024];
  __shared__ int sflag;
  int tid = threadIdx.x;
  if (tid < 64) {
    const long long* p = (const long long*)ei;
    long long v = p[tid];
    int bad = (v < 0 || v >= (long long)N) ? 1 : 0;
    unsigned long long mres = __ballot(bad);
    if (tid == 0) sflag = (mres == 0ull) ? 1 : 0;
  }
  for (int j = tid; j < nb; j += 256) hist[j] = 0;
  __syncthreads();
  int is64 = sflag;
  long long base = (long long)blockIdx.x * BCHUNK;
  int cnt = (int)min((long long)BCHUNK, (long long)M - base);
  for (int i = tid; i < cnt; i += 256) {
    long long g = base + i;
    int d = (g < E) ? edge_at(ei, is64, (long long)E + g) : (int)(g - E);
    atomicAdd(&hist[d >> 8], 1);
  }
  __syncthreads();
  for (int j = tid; j < nb; j += 256) counts[(size_t)j * nblk + blockIdx.x] = hist[j];
}

__global__ __launch_bounds__(1024) void k_binScan(int* counts, int total_entries) {
  __shared__ int part[1024];
  int tid = threadIdx.x;
  int per = (total_entries + 1023) / 1024;
  int lo = tid * per;
  int hi = lo + per; if (hi > total_entries) hi = total_entries;
  int s = 0;
  int i = lo;
  for (; i + 8 <= hi; i += 8) {
    int c0 = counts[i], c1 = counts[i + 1], c2 = counts[i + 2], c3 = counts[i + 3];
    int c4 = counts[i + 4], c5 = counts[i + 5], c6 = counts[i + 6], c7 = counts[i + 7];
    s += ((c0 + c1) + (c2 + c3)) + ((c4 + c5) + (c6 + c7));
  }
  for (; i < hi; ++i) s += counts[i];
  part[tid] = s;
  __syncthreads();
  for (int off = 1; off < 1024; off <<= 1) {
    int add = (tid >= off) ? part[tid - off] : 0;
    __syncthreads();
    part[tid] += add;
    __syncthreads();
  }
  int run = (tid == 0) ? 0 : part[tid - 1];
  i = lo;
  for (; i + 8 <= hi; i += 8) {
    int c0 = counts[i], c1 = counts[i + 1], c2 = counts[i + 2], c3 = counts[i + 3];
    int c4 = counts[i + 4], c5 = counts[i + 5], c6 = counts[i + 6], c7 = counts[i + 7];
    counts[i] = run; run += c0;
    counts[i + 1] = run; run += c1;
    counts[i + 2] = run; run += c2;
    counts[i + 3] = run; run += c3;
    counts[i + 4] = run; run += c4;
    counts[i + 5] = run; run += c5;
    counts[i + 6] = run; run += c6;
    counts[i + 7] = run; run += c7;
  }
  for (; i < hi; ++i) {
    int c = counts[i];
    counts[i] = run;
    run += c;
  }
}

__global__ __launch_bounds__(256) void k_binC(const void* ei, int N, int E, int M,
                                              int nb, int nblk, const int* counts, unsigned* tmp) {
  __shared__ int cur[1024];
  __shared__ int sflag;
  int tid = threadIdx.x;
  if (tid < 64) {
    const long long* p = (const long long*)ei;
    long long v = p[tid];
    int bad = (v < 0 || v >= (long long)N) ? 1 : 0;
    unsigned long long mres = __ballot(bad);
    if (tid == 0) sflag = (mres == 0ull) ? 1 : 0;
  }
  for (int j = tid; j < nb; j += 256) cur[j] = counts[(size_t)j * nblk + blockIdx.x];
  __syncthreads();
  int is64 = sflag;
  long long base = (long long)blockIdx.x * BCHUNK;
  int cnt = (int)min((long long)BCHUNK, (long long)M - base);
  for (int i = tid; i < cnt; i += 256) {
    long long g = base + i;
    int s, d;
    if (g < E) { s = edge_at(ei, is64, g); d = edge_at(ei, is64, (long long)E + g); }
    else       { s = d = (int)(g - E); }
    int pos = atomicAdd(&cur[d >> 8], 1);
    tmp[pos] = ((unsigned)s << 8) | (unsigned)(d & 255);
  }
}

__global__ __launch_bounds__(256) void k_binD(const unsigned* __restrict__ tmp,
                                              const int* __restrict__ counts,
                                              int nb, int nblk, int M, int N,
                                              int* __restrict__ rowptr, int* __restrict__ col) {
  __shared__ int scn[256];
  __shared__ int cur[256];
  int tid = threadIdx.x;
  int j = blockIdx.x;
  int base = counts[(size_t)j * nblk];
  int endv = (j + 1 < nb) ? counts[(size_t)(j + 1) * nblk] : M;
  int bc = endv - base;
  scn[tid] = 0;
  __syncthreads();
  for (int i = tid; i < bc; i += 256) atomicAdd(&scn[tmp[base + i] & 255], 1);
  __syncthreads();
  int v = scn[tid];
  __syncthreads();
  scn[tid] = v;
  __syncthreads();
  for (int off = 1; off < 256; off <<= 1) {
    int add = (tid >= off) ? scn[tid - off] : 0;
    __syncthreads();
    scn[tid] += add;
    __syncthreads();
  }
  int excl = scn[tid] - v;
  int d = (j << 8) + tid;
  if (d < N) rowptr[d] = base + excl;
  cur[tid] = base + excl;
  __syncthreads();
  for (int i = tid; i < bc; i += 256) {
    unsigned w = tmp[base + i];
    int pos = atomicAdd(&cur[w & 255], 1);
    col[pos] = (int)(w >> 8);
  }
  if (j == nb - 1 && tid == 0) rowptr[N] = M;
}

// ---------- combined prep: Bp frag-order + Wesed + layer-1 BN stats ----------
// blocks 0-15: Bp1; 16-31: Bp2; 32/33: Wesed1/2; 34..1057: stats of fp32 x
// into 8-replica slots stats1[(b&7)*256 + f].
__global__ __launch_bounds__(256) void k_prep(
    const float* __restrict__ W1, const float* __restrict__ LW1,
    const float* __restrict__ W2, const float* __restrict__ LW2,
    const float* __restrict__ as1, const float* __restrict__ ad1,
    const float* __restrict__ as2, const float* __restrict__ ad2,
    const float* __restrict__ x, int N,
    unsigned short* __restrict__ Bp1, unsigned short* __restrict__ Bp2,
    float4* __restrict__ Wesed1, float4* __restrict__ Wesed2,
    float* __restrict__ stats1) {
  int blk = blockIdx.x;
  int tid = threadIdx.x;
  if (blk >= 34) {
    int b = blk - 34;  // 0..1023
    int f = tid & 127;
    int half = tid >> 7;
    float s = 0.f, s2 = 0.f;
    for (int r = b + half * 1024; r < N; r += 2048) {
      float v = x[(size_t)r * 128 + f];
      s += v; s2 += v * v;
    }
    float* rep = stats1 + (size_t)(b & 7) * 256;
    atomicAdd(&rep[f], s);
    atomicAdd(&rep[128 + f], s2);
    return;
  }
  if (blk >= 32) {
    int k = tid;
    if (k >= 128) return;
    const float* W = (blk == 32) ? W1 : W2;
    const float* as_ = (blk == 32) ? as1 : as2;
    const float* ad_ = (blk == 32) ? ad1 : ad2;
    float4* out = (blk == 32) ? Wesed1 : Wesed2;
    float s0 = 0.f, s1 = 0.f, d0 = 0.f, d1 = 0.f;
    for (int f = 0; f < 64; ++f) {
      float w0 = W[k * 128 + f], w1 = W[k * 128 + 64 + f];
      s0 += w0 * as_[f];       d0 += w0 * ad_[f];
      s1 += w1 * as_[64 + f];  d1 += w1 * ad_[64 + f];
    }
    out[k] = make_float4(s0, s1, d0, d1);
    return;
  }
  const float* W  = (blk < 16) ? W1 : W2;
  const float* LW = (blk < 16) ? LW1 : LW2;
  unsigned short* Bp = (blk < 16) ? Bp1 : Bp2;
  int fi = (blk & 15) * 256 + tid;  // 4096 frags
  int lane = fi & 63, s = (fi >> 6) & 7, t = fi >> 9;
  int n = t * 32 + (lane & 31);
  int k0 = s * 16 + (lane >> 5) * 8;
  unsigned short tb[8];
#pragma unroll
  for (int j = 0; j < 8; ++j) {
    int k = k0 + j;
    float v = (n < 128) ? W[k * 128 + n] : LW[k * 128 + (n - 128)];
    tb[j] = bf16of(v);
  }
  uint4 pk;
  pk.x = (unsigned)tb[0] | ((unsigned)tb[1] << 16);
  pk.y = (unsigned)tb[2] | ((unsigned)tb[3] << 16);
  pk.z = (unsigned)tb[4] | ((unsigned)tb[5] << 16);
  pk.w = (unsigned)tb[6] | ((unsigned)tb[7] << 16);
  *(uint4*)&Bp[(size_t)fi * 8] = pk;
}

// ---------- MFMA matmul + fused es/ed; BN-fin from 8-replica stats ----------
__global__ __launch_bounds__(256) void k_mm(
    const void* __restrict__ xin, int packed,
    const float* __restrict__ stats, const float* __restrict__ gamma, const float* __restrict__ beta,
    const unsigned short* __restrict__ Bp, const float4* __restrict__ Wesed,
    unsigned* __restrict__ hb, unsigned* __restrict__ linp,
    float* __restrict__ es, float* __restrict__ ed, int N) {
  __shared__ __align__(16) unsigned short Al[32 * 136];
  __shared__ float scl_s[128], sht_s[128];
  __shared__ float4 wes_s[128];
  int tid = threadIdx.x;
  int lane = tid & 63;
  int w = tid >> 6;
  int rowBase = blockIdx.x * 32;

  if (tid < 128) {
    float s = 0.f, s2 = 0.f;
#pragma unroll
    for (int r = 0; r < 8; ++r) {
      s += stats[r * 256 + tid];
      s2 += stats[r * 256 + 128 + tid];
    }
    float inv_n = 1.0f / (float)N;
    float mu = s * inv_n;
    float var = s2 * inv_n - mu * mu;
    float rs = rsqrtf(var + BN_EPS);
    float sc = gamma[tid] * rs;
    scl_s[tid] = sc;
    sht_s[tid] = beta[tid] - mu * sc;
    wes_s[tid] = Wesed[tid];
  }

  v8bf bfrag[2][8];
#pragma unroll
  for (int t = 0; t < 2; ++t)
#pragma unroll
    for (int s = 0; s < 8; ++s) {
      int fi = ((2 * w + t) * 8 + s) * 64 + lane;
      bfrag[t][s] = *(const v8bf*)&Bp[(size_t)fi * 8];
    }
  __syncthreads();

  if (!packed) {
    const float* x = (const float*)xin;
    for (int q = tid; q < 32 * 32; q += 256) {
      int r = q >> 5, k4 = (q & 31) * 4;
      int row = rowBase + r;
      float4 v = make_float4(0.f, 0.f, 0.f, 0.f);
      if (row < N) v = *(const float4*)&x[(size_t)row * 128 + k4];
      unsigned p0 = pack_bf16(v.x * scl_s[k4] + sht_s[k4], v.y * scl_s[k4 + 1] + sht_s[k4 + 1]);
      unsigned p1 = pack_bf16(v.z * scl_s[k4 + 2] + sht_s[k4 + 2], v.w * scl_s[k4 + 3] + sht_s[k4 + 3]);
      *(uint2*)&Al[r * 136 + k4] = make_uint2(p0, p1);
    }
  } else {
    const unsigned* xp = (const unsigned*)xin;
    for (int q = tid; q < 32 * 16; q += 256) {
      int r = q >> 4, g = q & 15;
      int row = rowBase + r;
      uint4 u = make_uint4(0u, 0u, 0u, 0u);
      if (row < N) u = *(const uint4*)&xp[(size_t)row * 64 + g * 4];
      int f = g * 8;
      uint4 o;
      o.x = pack_bf16(blo(u.x) * scl_s[f] + sht_s[f], bhi(u.x) * scl_s[f + 1] + sht_s[f + 1]);
      o.y = pack_bf16(blo(u.y) * scl_s[f + 2] + sht_s[f + 2], bhi(u.y) * scl_s[f + 3] + sht_s[f + 3]);
      o.z = pack_bf16(blo(u.z) * scl_s[f + 4] + sht_s[f + 4], bhi(u.z) * scl_s[f + 5] + sht_s[f + 5]);
      o.w = pack_bf16(blo(u.w) * scl_s[f + 6] + sht_s[f + 6], bhi(u.w) * scl_s[f + 7] + sht_s[f + 7]);
      *(uint4*)&Al[r * 136 + f] = o;
    }
  }
  __syncthreads();

  int m = lane & 31, half = lane >> 5;
  v8bf afrag[8];
#pragma unroll
  for (int s = 0; s < 8; ++s)
    afrag[s] = *(const v8bf*)&Al[m * 136 + s * 16 + half * 8];

  v16f acc0 = {}, acc1 = {};
#pragma unroll
  for (int s = 0; s < 8; ++s) {
    acc0 = __builtin_amdgcn_mfma_f32_32x32x16_bf16(afrag[s], bfrag[0][s], acc0, 0, 0, 0);
    acc1 = __builtin_amdgcn_mfma_f32_32x32x16_bf16(afrag[s], bfrag[1][s], acc1, 0, 0, 0);
  }

  int mlo = half * 4;
  int t0 = 2 * w, t1 = 2 * w + 1;
#pragma unroll
  for (int r = 0; r < 16; ++r) {
    int row = (r & 3) + 8 * (r >> 2) + mlo;
    int node = rowBase + row;
    float a0 = acc0[r], a1 = acc1[r];
    float b0 = __shfl_xor(a0, 1, 64);
    float b1 = __shfl_xor(a1, 1, 64);
    if (node >= N || (lane & 1)) continue;
    if (t0 < 4) {
      hb[(size_t)node * 64 + (t0 * 16 + (m >> 1))] = pack_bf16(a0, b0);
      hb[(size_t)node * 64 + (t1 * 16 + (m >> 1))] = pack_bf16(a1, b1);
    } else {
      linp[(size_t)node * 64 + ((t0 - 4) * 16 + (m >> 1))] = pack_bf16(a0, b0);
      linp[(size_t)node * 64 + ((t1 - 4) * 16 + (m >> 1))] = pack_bf16(a1, b1);
    }
  }

  // fused es/ed: es = bf16(xn) @ (W@as) etc.; wave w handles rows 8w..8w+7
#pragma unroll
  for (int rr = 0; rr < 8; ++rr) {
    int row = 8 * w + rr;
    int node = rowBase + row;
    unsigned ua = *(const unsigned*)&Al[row * 136 + 2 * lane];
    float va = blo(ua), vb = bhi(ua);
    float4 wa = wes_s[2 * lane];
    float4 wb = wes_s[2 * lane + 1];
    float p0 = va * wa.x + vb * wb.x;
    float p1 = va * wa.y + vb * wb.y;
    float p2 = va * wa.z + vb * wb.z;
    float p3 = va * wa.w + vb * wb.w;
    p0 = wsum(p0); p1 = wsum(p1); p2 = wsum(p2); p3 = wsum(p3);
    if (lane == 0 && node < N) {
      *(float2*)&es[2 * node] = make_float2(p0, p1);
      *(float2*)&ed[2 * node] = make_float2(p2, p3);
    }
  }
}

// ---------- single-pass edge aggregation + combine + next-layer BN stats ----------
// 16 lanes x uint4 per edge (256B row), 4 edges/inst group, 4x unroll.
// Packed v2f math (v_pk_* ops). q==0 lanes atomically add their 8 final
// values into 8-replica global stats (blockIdx&7) for the next layer's BN.
__global__ __launch_bounds__(256) void k_agg(
    const int* __restrict__ rowptr, const int* __restrict__ col,
    const float* __restrict__ es, const float* __restrict__ ed,
    const unsigned* __restrict__ hb, const unsigned* __restrict__ linp,
    const float* __restrict__ lb, const float* __restrict__ gb,
    unsigned* __restrict__ xoutp, float* __restrict__ statsOut, int N) {
  int lane = threadIdx.x & 63;
  int w = threadIdx.x >> 6;
  int d = blockIdx.x * 4 + w;
  if (d >= N) return;
  int start = rowptr[d], end = rowptr[d + 1];
  v2f edv = *(const v2f*)&ed[2 * d];
  int q = lane >> 4;   // edge quarter 0..3
  int m = lane & 15;   // feats 8m..8m+7
  int head_hi = m >= 8;
  v2f zero = {0.f, 0.f};
  v2f lk = {LEAKY, LEAKY};

  v2f acc[4] = {zero, zero, zero, zero};
  v2f sp = zero;
  int i = start;
  for (; i + 16 <= end; i += 16) {
#pragma unroll
    for (int b = 0; b < 4; ++b) {
      int idx = i + 4 * b + q;
      int s = col[idx];
      v2f ev = *(const v2f*)&es[2 * s];
      uint4 u = *(const uint4*)&hb[(size_t)s * 64 + m * 4];
      v2f e = ev + edv;
      v2f le = __builtin_elementwise_max(e, zero) + lk * __builtin_elementwise_min(e, zero);
      v2f p; p.x = __expf(le.x); p.y = __expf(le.y);
      sp += p;
      float f = head_hi ? p.y : p.x;
      v2f fv = {f, f};
      acc[0] = __builtin_elementwise_fma(fv, bpair(u.x), acc[0]);
      acc[1] = __builtin_elementwise_fma(fv, bpair(u.y), acc[1]);
      acc[2] = __builtin_elementwise_fma(fv, bpair(u.z), acc[2]);
      acc[3] = __builtin_elementwise_fma(fv, bpair(u.w), acc[3]);
    }
  }
  for (; i < end; i += 4) {  // masked tail, 4 edges/iter
    int idx = i + q;
    int valid = idx < end;
    int s = col[valid ? idx : end - 1];
    v2f ev = *(const v2f*)&es[2 * s];
    uint4 u = *(const uint4*)&hb[(size_t)s * 64 + m * 4];
    v2f e = ev + edv;
    v2f le = __builtin_elementwise_max(e, zero) + lk * __builtin_elementwise_min(e, zero);
    v2f p; p.x = __expf(le.x); p.y = __expf(le.y);
    if (!valid) p = zero;
    sp += p;
    float f = head_hi ? p.y : p.x;
    v2f fv = {f, f};
    acc[0] = __builtin_elementwise_fma(fv, bpair(u.x), acc[0]);
    acc[1] = __builtin_elementwise_fma(fv, bpair(u.y), acc[1]);
    acc[2] = __builtin_elementwise_fma(fv, bpair(u.z), acc[2]);
    acc[3] = __builtin_elementwise_fma(fv, bpair(u.w), acc[3]);
  }
  // reduce across quarters
#pragma unroll
  for (int k = 0; k < 4; ++k) {
    acc[k].x += __shfl_xor(acc[k].x, 16, 64);
    acc[k].x += __shfl_xor(acc[k].x, 32, 64);
    acc[k].y += __shfl_xor(acc[k].y, 16, 64);
    acc[k].y += __shfl_xor(acc[k].y, 32, 64);
  }
  sp.x += __shfl_xor(sp.x, 16, 64); sp.x += __shfl_xor(sp.x, 32, 64);
  sp.y += __shfl_xor(sp.y, 16, 64); sp.y += __shfl_xor(sp.y, 32, 64);

  if (q == 0) {
    float inv = 1.0f / (head_hi ? sp.y : sp.x);
    uint4 lv = *(const uint4*)&linp[(size_t)d * 64 + m * 4];
    int f8 = 8 * m;
    float4 lb0 = *(const float4*)&lb[f8], lb1 = *(const float4*)&lb[f8 + 4];
    float4 gb0 = *(const float4*)&gb[f8], gb1 = *(const float4*)&gb[f8 + 4];
    float v0 = blo(lv.x) + lb0.x + acc[0].x * inv + gb0.x;
    float v1 = bhi(lv.x) + lb0.y + acc[0].y * inv + gb0.y;
    float v2 = blo(lv.y) + lb0.z + acc[1].x * inv + gb0.z;
    float v3 = bhi(lv.y) + lb0.w + acc[1].y * inv + gb0.w;
    float v4 = blo(lv.z) + lb1.x + acc[2].x * inv + gb1.x;
    float v5 = bhi(lv.z) + lb1.y + acc[2].y * inv + gb1.y;
    float v6 = blo(lv.w) + lb1.z + acc[3].x * inv + gb1.z;
    float v7 = bhi(lv.w) + lb1.w + acc[3].y * inv + gb1.w;
    v0 = v0 > 0.f ? v0 : 0.f; v1 = v1 > 0.f ? v1 : 0.f;
    v2 = v2 > 0.f ? v2 : 0.f; v3 = v3 > 0.f ? v3 : 0.f;
    v4 = v4 > 0.f ? v4 : 0.f; v5 = v5 > 0.f ? v5 : 0.f;
    v6 = v6 > 0.f ? v6 : 0.f; v7 = v7 > 0.f ? v7 : 0.f;
    uint4 o;
    o.x = pack_bf16(v0, v1); o.y = pack_bf16(v2, v3);
    o.z = pack_bf16(v4, v5); o.w = pack_bf16(v6, v7);
    *(uint4*)&xoutp[(size_t)d * 64 + m * 4] = o;
    // next-layer BN stats into 8-replica slots
    float* rep = statsOut + (size_t)(blockIdx.x & 7) * 256;
    atomicAdd(&rep[f8 + 0], v0); atomicAdd(&rep[128 + f8 + 0], v0 * v0);
    atomicAdd(&rep[f8 + 1], v1); atomicAdd(&rep[128 + f8 + 1], v1 * v1);
    atomicAdd(&rep[f8 + 2], v2); atomicAdd(&rep[128 + f8 + 2], v2 * v2);
    atomicAdd(&rep[f8 + 3], v3); atomicAdd(&rep[128 + f8 + 3], v3 * v3);
    atomicAdd(&rep[f8 + 4], v4); atomicAdd(&rep[128 + f8 + 4], v4 * v4);
    atomicAdd(&rep[f8 + 5], v5); atomicAdd(&rep[128 + f8 + 5], v5 * v5);
    atomicAdd(&rep[f8 + 6], v6); atomicAdd(&rep[128 + f8 + 6], v6 * v6);
    atomicAdd(&rep[f8 + 7], v7); atomicAdd(&rep[128 + f8 + 7], v7 * v7);
  }
}

// ---------- layer 3: BN(inline, 8-replica stats) + tiny matmul + es/ed ----------
__global__ __launch_bounds__(256) void k_l3node(
    const unsigned* __restrict__ xp,
    const float* __restrict__ stats, const float* __restrict__ gamma, const float* __restrict__ beta,
    const float* __restrict__ W3, const float* __restrict__ LW3,
    const float* __restrict__ as3, const float* __restrict__ ad3,
    float* h3, float* lin3, float* es3, float* ed3, int N) {
  int lane = threadIdx.x & 63;
  int n = blockIdx.x * 4 + (threadIdx.x >> 6);
  if (n >= N) return;
  float inv_n = 1.0f / (float)N;
  int f0 = lane, f1 = 64 + lane;
  float su0 = 0.f, sq0 = 0.f, su1 = 0.f, sq1 = 0.f;
#pragma unroll
  for (int r = 0; r < 8; ++r) {
    su0 += stats[r * 256 + f0];  sq0 += stats[r * 256 + 128 + f0];
    su1 += stats[r * 256 + f1];  sq1 += stats[r * 256 + 128 + f1];
  }
  float mu0 = su0 * inv_n;
  float var0 = sq0 * inv_n - mu0 * mu0;
  float rs0 = rsqrtf(var0 + BN_EPS);
  float sc0 = gamma[f0] * rs0, sh0 = beta[f0] - mu0 * sc0;
  float mu1 = su1 * inv_n;
  float var1 = sq1 * inv_n - mu1 * mu1;
  float rs1 = rsqrtf(var1 + BN_EPS);
  float sc1 = gamma[f1] * rs1, sh1 = beta[f1] - mu1 * sc1;

  unsigned ua = xp[(size_t)n * 64 + (lane >> 1)];
  unsigned ub = xp[(size_t)n * 64 + 32 + (lane >> 1)];
  float xv0 = (lane & 1) ? bhi(ua) : blo(ua);
  float xv1 = (lane & 1) ? bhi(ub) : blo(ub);
  float xn0 = xv0 * sc0 + sh0;
  float xn1 = xv1 * sc1 + sh1;

  float2 w0 = *(const float2*)&W3[lane * 2];
  float2 w1 = *(const float2*)&W3[(64 + lane) * 2];
  float2 l0 = *(const float2*)&LW3[lane * 2];
  float2 l1 = *(const float2*)&LW3[(64 + lane) * 2];
  float hc0 = wsum(xn0 * w0.x + xn1 * w1.x);
  float hc1 = wsum(xn0 * w0.y + xn1 * w1.y);
  float lc0 = wsum(xn0 * l0.x + xn1 * l1.x);
  float lc1 = wsum(xn0 * l0.y + xn1 * l1.y);
  if (lane == 0) {
    h3[2 * n] = hc0; h3[2 * n + 1] = hc1;
    lin3[2 * n] = lc0; lin3[2 * n + 1] = lc1;
    es3[n] = hc0 * as3[0] + hc1 * as3[1];
    ed3[n] = hc0 * ad3[0] + hc1 * ad3[1];
  }
}

// ---------- layer 3 edge aggregation + final output ----------
__global__ __launch_bounds__(256) void k_agg3(
    const int* __restrict__ rowptr, const int* __restrict__ col,
    const float* __restrict__ es, const float* __restrict__ ed,
    const float* __restrict__ h3, const float* __restrict__ lin3,
    const float* __restrict__ lb3, const float* __restrict__ gb3,
    float* __restrict__ out, int N) {
  int lane = threadIdx.x & 63;
  int d = blockIdx.x * 4 + (threadIdx.x >> 6);
  if (d >= N) return;
  int start = rowptr[d], end = rowptr[d + 1];
  float edd = ed[d];
  float ps = 0.f, a0 = 0.f, a1 = 0.f;
  for (int i = start + lane; i < end; i += 64) {
    int s = col[i];
    float e = es[s] + edd; e = e > 0.f ? e : LEAKY * e;
    float p = __expf(e);
    float2 hv = *(const float2*)&h3[2 * s];
    ps += p; a0 += p * hv.x; a1 += p * hv.y;
  }
  ps = wsum(ps); a0 = wsum(a0); a1 = wsum(a1);
  if (lane < 2) {
    float a = (lane == 0 ? a0 : a1) / ps;
    float v = lin3[2 * d + lane] + lb3[lane] + a + gb3[lane];
    out[2 * d + lane] = v > 0.f ? v : 0.f;
  }
}

extern "C" void kernel_launch(void* const* d_in, const int* in_sizes, int n_in,
                              void* d_out, int out_size, void* d_ws, size_t ws_size,
                              hipStream_t stream) {
  const float* x   = (const float*)d_in[0];
  const void*  ei  = d_in[1];
  const float* W1  = (const float*)d_in[2];
  const float* as1 = (const float*)d_in[3];
  const float* ad1 = (const float*)d_in[4];
  const float* gb1 = (const float*)d_in[5];
  const float* lw1 = (const float*)d_in[6];
  const float* lb1 = (const float*)d_in[7];
  const float* bg1 = (const float*)d_in[8];
  const float* bb1 = (const float*)d_in[9];
  const float* W2  = (const float*)d_in[10];
  const float* as2 = (const float*)d_in[11];
  const float* ad2 = (const float*)d_in[12];
  const float* gb2 = (const float*)d_in[13];
  const float* lw2 = (const float*)d_in[14];
  const float* lb2 = (const float*)d_in[15];
  const float* bg2 = (const float*)d_in[16];
  const float* bb2 = (const float*)d_in[17];
  const float* W3  = (const float*)d_in[18];
  const float* as3 = (const float*)d_in[19];
  const float* ad3 = (const float*)d_in[20];
  const float* gb3 = (const float*)d_in[21];
  const float* lw3 = (const float*)d_in[22];
  const float* lb3 = (const float*)d_in[23];
  const float* bg3 = (const float*)d_in[24];
  const float* bb3 = (const float*)d_in[25];
  float* out = (float*)d_out;

  int N = in_sizes[0] / 128;
  int E = in_sizes[1] / 2;
  int M = E + N;
  int nb = (N + 255) >> 8;
  int nblk = (M + BCHUNK - 1) / BCHUNK;

  char* wsp = (char*)d_ws;
  size_t off = 0;
  auto alloc = [&](size_t bytes) -> void* {
    void* p = wsp + off;
    off = (off + bytes + 255) & ~(size_t)255;
    return p;
  };
  int* rowptr   = (int*)alloc(((size_t)N + 1) * 4);
  int* col      = (int*)alloc((size_t)M * 4);
  unsigned* tmp = (unsigned*)alloc((size_t)M * 4);
  int* counts   = (int*)alloc(((size_t)nb * nblk + 1) * 4);
  float* st1    = (float*)alloc(8 * 256 * 4);
  float* st2    = (float*)alloc(8 * 256 * 4);
  float* st3    = (float*)alloc(8 * 256 * 4);
  unsigned short* Bp1 = (unsigned short*)alloc(4096 * 16);
  unsigned short* Bp2 = (unsigned short*)alloc(4096 * 16);
  float4* Wesed1 = (float4*)alloc(128 * 16);
  float4* Wesed2 = (float4*)alloc(128 * 16);
  unsigned* hbp  = (unsigned*)alloc((size_t)N * 64 * 4);
  unsigned* linp = (unsigned*)alloc((size_t)N * 64 * 4);
  unsigned* x2p  = (unsigned*)alloc((size_t)N * 64 * 4);
  float* es    = (float*)alloc((size_t)N * 2 * 4);
  float* edb   = (float*)alloc((size_t)N * 2 * 4);
  float* h3    = (float*)alloc((size_t)N * 2 * 4);
  float* lin3  = (float*)alloc((size_t)N * 2 * 4);
  float* es3   = (float*)alloc((size_t)N * 4);
  float* ed3   = (float*)alloc((size_t)N * 4);
  (void)ws_size; (void)n_in; (void)out_size;

  hipMemsetAsync(st1, 0, 3 * 8 * 256 * 4, stream);  // st1,st2,st3 contiguous

  // CSR build (probe inlined into binA/binC)
  k_binA<<<nblk, 256, 0, stream>>>(ei, N, E, M, nb, nblk, counts);
  k_binScan<<<1, 1024, 0, stream>>>(counts, nb * nblk);
  k_binC<<<nblk, 256, 0, stream>>>(ei, N, E, M, nb, nblk, counts, tmp);
  k_binD<<<nb, 256, 0, stream>>>(tmp, counts, nb, nblk, M, N, rowptr, col);

  // combined weight prep + layer-1 BN stats
  k_prep<<<34 + 1024, 256, 0, stream>>>(W1, lw1, W2, lw2, as1, ad1, as2, ad2,
                                        x, N, Bp1, Bp2, Wesed1, Wesed2, st1);

  int gnode = (N + 3) / 4;
  int gmm = (N + 31) / 32;

  // ---- layer 1 ----
  k_mm<<<gmm, 256, 0, stream>>>(x, 0, st1, bg1, bb1, Bp1, Wesed1, hbp, linp, es, edb, N);
  k_agg<<<gnode, 256, 0, stream>>>(rowptr, col, es, edb, hbp, linp, lb1, gb1, x2p, st2, N);

  // ---- layer 2 ----
  k_mm<<<gmm, 256, 0, stream>>>(x2p, 1, st2, bg2, bb2, Bp2, Wesed2, hbp, linp, es, edb, N);
  k_agg<<<gnode, 256, 0, stream>>>(rowptr, col, es, edb, hbp, linp, lb2, gb2, x2p, st3, N);

  // ---- layer 3 ----
  k_l3node<<<gnode, 256, 0, stream>>>(x2p, st3, bg3, bb3, W3, lw3, as3, ad3,
                                      h3, lin3, es3, ed3, N);
  k_agg3<<<gnode, 256, 0, stream>>>(rowptr, col, es3, ed3, h3, lin3, lb3, gb3, out, N);
}

// Round 10
// 454.529 us; speedup vs baseline: 8.7401x; 8.7401x over previous
//
#include <hip/hip_runtime.h>

#define LEAKY 0.2f
#define BN_EPS 1e-5f
#define BCHUNK 8192

typedef __bf16 v8bf __attribute__((ext_vector_type(8)));
typedef float v16f __attribute__((ext_vector_type(16)));
typedef float v2f __attribute__((ext_vector_type(2)));

// ---------- wave helpers (wave64) ----------
__device__ __forceinline__ float wsum(float v) {
#pragma unroll
  for (int o = 32; o > 0; o >>= 1) v += __shfl_xor(v, o, 64);
  return v;
}

// packed-bf16: dword holds feat2j (low16) and feat2j+1 (high16)
__device__ __forceinline__ float blo(unsigned u) { return __uint_as_float(u << 16); }
__device__ __forceinline__ float bhi(unsigned u) { return __uint_as_float(u & 0xffff0000u); }
__device__ __forceinline__ v2f bpair(unsigned u) {
  v2f r; r.x = __uint_as_float(u << 16); r.y = __uint_as_float(u & 0xffff0000u); return r;
}
__device__ __forceinline__ unsigned pack_bf16(float a, float b) {
  unsigned ua = __float_as_uint(a), ub = __float_as_uint(b);
  ua = (ua + 0x7fffu + ((ua >> 16) & 1u)) >> 16;
  ub = (ub + 0x7fffu + ((ub >> 16) & 1u)) >> 16;
  return ua | (ub << 16);
}
__device__ __forceinline__ unsigned short bf16of(float a) {
  unsigned ua = __float_as_uint(a);
  return (unsigned short)((ua + 0x7fffu + ((ua >> 16) & 1u)) >> 16);
}

// edge_index may be int64 (reference dtype) or int32 (JAX x64 disabled).
__device__ __forceinline__ int edge_at(const void* ei, int is64, long long i) {
  return is64 ? (int)((const long long*)ei)[i] : ((const int*)ei)[i];
}

// ---------- CSR build: two-level counting sort (write-local) ----------
__global__ __launch_bounds__(256) void k_binA(const void* ei, int N, int E, int M,
                                              int nb, int nblk, int* counts) {
  __shared__ int hist[1024];
  __shared__ int sflag;
  int tid = threadIdx.x;
  if (tid < 64) {
    const long long* p = (const long long*)ei;
    long long v = p[tid];
    int bad = (v < 0 || v >= (long long)N) ? 1 : 0;
    unsigned long long mres = __ballot(bad);
    if (tid == 0) sflag = (mres == 0ull) ? 1 : 0;
  }
  for (int j = tid; j < nb; j += 256) hist[j] = 0;
  __syncthreads();
  int is64 = sflag;
  long long base = (long long)blockIdx.x * BCHUNK;
  int cnt = (int)min((long long)BCHUNK, (long long)M - base);
  for (int i = tid; i < cnt; i += 256) {
    long long g = base + i;
    int d = (g < E) ? edge_at(ei, is64, (long long)E + g) : (int)(g - E);
    atomicAdd(&hist[d >> 8], 1);
  }
  __syncthreads();
  for (int j = tid; j < nb; j += 256) counts[(size_t)j * nblk + blockIdx.x] = hist[j];
}

__global__ __launch_bounds__(1024) void k_binScan(int* counts, int total_entries) {
  __shared__ int part[1024];
  int tid = threadIdx.x;
  int per = (total_entries + 1023) / 1024;
  int lo = tid * per;
  int hi = lo + per; if (hi > total_entries) hi = total_entries;
  int s = 0;
  int i = lo;
  for (; i + 8 <= hi; i += 8) {
    int c0 = counts[i], c1 = counts[i + 1], c2 = counts[i + 2], c3 = counts[i + 3];
    int c4 = counts[i + 4], c5 = counts[i + 5], c6 = counts[i + 6], c7 = counts[i + 7];
    s += ((c0 + c1) + (c2 + c3)) + ((c4 + c5) + (c6 + c7));
  }
  for (; i < hi; ++i) s += counts[i];
  part[tid] = s;
  __syncthreads();
  for (int off = 1; off < 1024; off <<= 1) {
    int add = (tid >= off) ? part[tid - off] : 0;
    __syncthreads();
    part[tid] += add;
    __syncthreads();
  }
  int run = (tid == 0) ? 0 : part[tid - 1];
  i = lo;
  for (; i + 8 <= hi; i += 8) {
    int c0 = counts[i], c1 = counts[i + 1], c2 = counts[i + 2], c3 = counts[i + 3];
    int c4 = counts[i + 4], c5 = counts[i + 5], c6 = counts[i + 6], c7 = counts[i + 7];
    counts[i] = run; run += c0;
    counts[i + 1] = run; run += c1;
    counts[i + 2] = run; run += c2;
    counts[i + 3] = run; run += c3;
    counts[i + 4] = run; run += c4;
    counts[i + 5] = run; run += c5;
    counts[i + 6] = run; run += c6;
    counts[i + 7] = run; run += c7;
  }
  for (; i < hi; ++i) {
    int c = counts[i];
    counts[i] = run;
    run += c;
  }
}

__global__ __launch_bounds__(256) void k_binC(const void* ei, int N, int E, int M,
                                              int nb, int nblk, const int* counts, unsigned* tmp) {
  __shared__ int cur[1024];
  __shared__ int sflag;
  int tid = threadIdx.x;
  if (tid < 64) {
    const long long* p = (const long long*)ei;
    long long v = p[tid];
    int bad = (v < 0 || v >= (long long)N) ? 1 : 0;
    unsigned long long mres = __ballot(bad);
    if (tid == 0) sflag = (mres == 0ull) ? 1 : 0;
  }
  for (int j = tid; j < nb; j += 256) cur[j] = counts[(size_t)j * nblk + blockIdx.x];
  __syncthreads();
  int is64 = sflag;
  long long base = (long long)blockIdx.x * BCHUNK;
  int cnt = (int)min((long long)BCHUNK, (long long)M - base);
  for (int i = tid; i < cnt; i += 256) {
    long long g = base + i;
    int s, d;
    if (g < E) { s = edge_at(ei, is64, g); d = edge_at(ei, is64, (long long)E + g); }
    else       { s = d = (int)(g - E); }
    int pos = atomicAdd(&cur[d >> 8], 1);
    tmp[pos] = ((unsigned)s << 8) | (unsigned)(d & 255);
  }
}

__global__ __launch_bounds__(256) void k_binD(const unsigned* __restrict__ tmp,
                                              const int* __restrict__ counts,
                                              int nb, int nblk, int M, int N,
                                              int* __restrict__ rowptr, int* __restrict__ col) {
  __shared__ int scn[256];
  __shared__ int cur[256];
  int tid = threadIdx.x;
  int j = blockIdx.x;
  int base = counts[(size_t)j * nblk];
  int endv = (j + 1 < nb) ? counts[(size_t)(j + 1) * nblk] : M;
  int bc = endv - base;
  scn[tid] = 0;
  __syncthreads();
  for (int i = tid; i < bc; i += 256) atomicAdd(&scn[tmp[base + i] & 255], 1);
  __syncthreads();
  int v = scn[tid];
  __syncthreads();
  scn[tid] = v;
  __syncthreads();
  for (int off = 1; off < 256; off <<= 1) {
    int add = (tid >= off) ? scn[tid - off] : 0;
    __syncthreads();
    scn[tid] += add;
    __syncthreads();
  }
  int excl = scn[tid] - v;
  int d = (j << 8) + tid;
  if (d < N) rowptr[d] = base + excl;
  cur[tid] = base + excl;
  __syncthreads();
  for (int i = tid; i < bc; i += 256) {
    unsigned w = tmp[base + i];
    int pos = atomicAdd(&cur[w & 255], 1);
    col[pos] = (int)(w >> 8);
  }
  if (j == nb - 1 && tid == 0) rowptr[N] = M;
}

// ---------- BatchNorm stats for packed-bf16 input (layers 2/3) ----------
__global__ __launch_bounds__(128) void k_bnstats(const unsigned* __restrict__ xp,
                                                 int N, float* sums) {
  int f = threadIdx.x;
  int q = f >> 1, hi = f & 1;
  float s = 0.f, s2 = 0.f;
  for (int r = blockIdx.x; r < N; r += gridDim.x) {
    unsigned u = xp[(size_t)r * 64 + q];
    float v = hi ? bhi(u) : blo(u);
    s += v; s2 += v * v;
  }
  float* rep = sums + (size_t)(blockIdx.x & 7) * 256;
  atomicAdd(&rep[f], s);
  atomicAdd(&rep[128 + f], s2);
}

// ---------- combined prep: Bp frag-order + Wesed + layer-1 BN stats ----------
// blocks 0-15: Bp1; 16-31: Bp2; 32/33: Wesed1/2; 34..1057: stats of fp32 x
// into 8-replica slots stats1[(b&7)*256 + f].
__global__ __launch_bounds__(256) void k_prep(
    const float* __restrict__ W1, const float* __restrict__ LW1,
    const float* __restrict__ W2, const float* __restrict__ LW2,
    const float* __restrict__ as1, const float* __restrict__ ad1,
    const float* __restrict__ as2, const float* __restrict__ ad2,
    const float* __restrict__ x, int N,
    unsigned short* __restrict__ Bp1, unsigned short* __restrict__ Bp2,
    float4* __restrict__ Wesed1, float4* __restrict__ Wesed2,
    float* __restrict__ stats1) {
  int blk = blockIdx.x;
  int tid = threadIdx.x;
  if (blk >= 34) {
    int b = blk - 34;  // 0..1023
    int f = tid & 127;
    int half = tid >> 7;
    float s = 0.f, s2 = 0.f;
    for (int r = b + half * 1024; r < N; r += 2048) {
      float v = x[(size_t)r * 128 + f];
      s += v; s2 += v * v;
    }
    float* rep = stats1 + (size_t)(b & 7) * 256;
    atomicAdd(&rep[f], s);
    atomicAdd(&rep[128 + f], s2);
    return;
  }
  if (blk >= 32) {
    int k = tid;
    if (k >= 128) return;
    const float* W = (blk == 32) ? W1 : W2;
    const float* as_ = (blk == 32) ? as1 : as2;
    const float* ad_ = (blk == 32) ? ad1 : ad2;
    float4* out = (blk == 32) ? Wesed1 : Wesed2;
    float s0 = 0.f, s1 = 0.f, d0 = 0.f, d1 = 0.f;
    for (int f = 0; f < 64; ++f) {
      float w0 = W[k * 128 + f], w1 = W[k * 128 + 64 + f];
      s0 += w0 * as_[f];       d0 += w0 * ad_[f];
      s1 += w1 * as_[64 + f];  d1 += w1 * ad_[64 + f];
    }
    out[k] = make_float4(s0, s1, d0, d1);
    return;
  }
  const float* W  = (blk < 16) ? W1 : W2;
  const float* LW = (blk < 16) ? LW1 : LW2;
  unsigned short* Bp = (blk < 16) ? Bp1 : Bp2;
  int fi = (blk & 15) * 256 + tid;  // 4096 frags
  int lane = fi & 63, s = (fi >> 6) & 7, t = fi >> 9;
  int n = t * 32 + (lane & 31);
  int k0 = s * 16 + (lane >> 5) * 8;
  unsigned short tb[8];
#pragma unroll
  for (int j = 0; j < 8; ++j) {
    int k = k0 + j;
    float v = (n < 128) ? W[k * 128 + n] : LW[k * 128 + (n - 128)];
    tb[j] = bf16of(v);
  }
  uint4 pk;
  pk.x = (unsigned)tb[0] | ((unsigned)tb[1] << 16);
  pk.y = (unsigned)tb[2] | ((unsigned)tb[3] << 16);
  pk.z = (unsigned)tb[4] | ((unsigned)tb[5] << 16);
  pk.w = (unsigned)tb[6] | ((unsigned)tb[7] << 16);
  *(uint4*)&Bp[(size_t)fi * 8] = pk;
}

// ---------- MFMA matmul + fused es/ed; BN-fin from 8-replica stats ----------
__global__ __launch_bounds__(256) void k_mm(
    const void* __restrict__ xin, int packed,
    const float* __restrict__ stats, const float* __restrict__ gamma, const float* __restrict__ beta,
    const unsigned short* __restrict__ Bp, const float4* __restrict__ Wesed,
    unsigned* __restrict__ hb, unsigned* __restrict__ linp,
    float* __restrict__ es, float* __restrict__ ed, int N) {
  __shared__ __align__(16) unsigned short Al[32 * 136];
  __shared__ float scl_s[128], sht_s[128];
  __shared__ float4 wes_s[128];
  int tid = threadIdx.x;
  int lane = tid & 63;
  int w = tid >> 6;
  int rowBase = blockIdx.x * 32;

  if (tid < 128) {
    float s = 0.f, s2 = 0.f;
#pragma unroll
    for (int r = 0; r < 8; ++r) {
      s += stats[r * 256 + tid];
      s2 += stats[r * 256 + 128 + tid];
    }
    float inv_n = 1.0f / (float)N;
    float mu = s * inv_n;
    float var = s2 * inv_n - mu * mu;
    float rs = rsqrtf(var + BN_EPS);
    float sc = gamma[tid] * rs;
    scl_s[tid] = sc;
    sht_s[tid] = beta[tid] - mu * sc;
    wes_s[tid] = Wesed[tid];
  }

  v8bf bfrag[2][8];
#pragma unroll
  for (int t = 0; t < 2; ++t)
#pragma unroll
    for (int s = 0; s < 8; ++s) {
      int fi = ((2 * w + t) * 8 + s) * 64 + lane;
      bfrag[t][s] = *(const v8bf*)&Bp[(size_t)fi * 8];
    }
  __syncthreads();

  if (!packed) {
    const float* x = (const float*)xin;
    for (int q = tid; q < 32 * 32; q += 256) {
      int r = q >> 5, k4 = (q & 31) * 4;
      int row = rowBase + r;
      float4 v = make_float4(0.f, 0.f, 0.f, 0.f);
      if (row < N) v = *(const float4*)&x[(size_t)row * 128 + k4];
      unsigned p0 = pack_bf16(v.x * scl_s[k4] + sht_s[k4], v.y * scl_s[k4 + 1] + sht_s[k4 + 1]);
      unsigned p1 = pack_bf16(v.z * scl_s[k4 + 2] + sht_s[k4 + 2], v.w * scl_s[k4 + 3] + sht_s[k4 + 3]);
      *(uint2*)&Al[r * 136 + k4] = make_uint2(p0, p1);
    }
  } else {
    const unsigned* xp = (const unsigned*)xin;
    for (int q = tid; q < 32 * 16; q += 256) {
      int r = q >> 4, g = q & 15;
      int row = rowBase + r;
      uint4 u = make_uint4(0u, 0u, 0u, 0u);
      if (row < N) u = *(const uint4*)&xp[(size_t)row * 64 + g * 4];
      int f = g * 8;
      uint4 o;
      o.x = pack_bf16(blo(u.x) * scl_s[f] + sht_s[f], bhi(u.x) * scl_s[f + 1] + sht_s[f + 1]);
      o.y = pack_bf16(blo(u.y) * scl_s[f + 2] + sht_s[f + 2], bhi(u.y) * scl_s[f + 3] + sht_s[f + 3]);
      o.z = pack_bf16(blo(u.z) * scl_s[f + 4] + sht_s[f + 4], bhi(u.z) * scl_s[f + 5] + sht_s[f + 5]);
      o.w = pack_bf16(blo(u.w) * scl_s[f + 6] + sht_s[f + 6], bhi(u.w) * scl_s[f + 7] + sht_s[f + 7]);
      *(uint4*)&Al[r * 136 + f] = o;
    }
  }
  __syncthreads();

  int m = lane & 31, half = lane >> 5;
  v8bf afrag[8];
#pragma unroll
  for (int s = 0; s < 8; ++s)
    afrag[s] = *(const v8bf*)&Al[m * 136 + s * 16 + half * 8];

  v16f acc0 = {}, acc1 = {};
#pragma unroll
  for (int s = 0; s < 8; ++s) {
    acc0 = __builtin_amdgcn_mfma_f32_32x32x16_bf16(afrag[s], bfrag[0][s], acc0, 0, 0, 0);
    acc1 = __builtin_amdgcn_mfma_f32_32x32x16_bf16(afrag[s], bfrag[1][s], acc1, 0, 0, 0);
  }

  int mlo = half * 4;
  int t0 = 2 * w, t1 = 2 * w + 1;
#pragma unroll
  for (int r = 0; r < 16; ++r) {
    int row = (r & 3) + 8 * (r >> 2) + mlo;
    int node = rowBase + row;
    float a0 = acc0[r], a1 = acc1[r];
    float b0 = __shfl_xor(a0, 1, 64);
    float b1 = __shfl_xor(a1, 1, 64);
    if (node >= N || (lane & 1)) continue;
    if (t0 < 4) {
      hb[(size_t)node * 64 + (t0 * 16 + (m >> 1))] = pack_bf16(a0, b0);
      hb[(size_t)node * 64 + (t1 * 16 + (m >> 1))] = pack_bf16(a1, b1);
    } else {
      linp[(size_t)node * 64 + ((t0 - 4) * 16 + (m >> 1))] = pack_bf16(a0, b0);
      linp[(size_t)node * 64 + ((t1 - 4) * 16 + (m >> 1))] = pack_bf16(a1, b1);
    }
  }

  // fused es/ed: es = bf16(xn) @ (W@as) etc.; wave w handles rows 8w..8w+7
#pragma unroll
  for (int rr = 0; rr < 8; ++rr) {
    int row = 8 * w + rr;
    int node = rowBase + row;
    unsigned ua = *(const unsigned*)&Al[row * 136 + 2 * lane];
    float va = blo(ua), vb = bhi(ua);
    float4 wa = wes_s[2 * lane];
    float4 wb = wes_s[2 * lane + 1];
    float p0 = va * wa.x + vb * wb.x;
    float p1 = va * wa.y + vb * wb.y;
    float p2 = va * wa.z + vb * wb.z;
    float p3 = va * wa.w + vb * wb.w;
    p0 = wsum(p0); p1 = wsum(p1); p2 = wsum(p2); p3 = wsum(p3);
    if (lane == 0 && node < N) {
      *(float2*)&es[2 * node] = make_float2(p0, p1);
      *(float2*)&ed[2 * node] = make_float2(p2, p3);
    }
  }
}

// ---------- single-pass edge aggregation + combine; one wave per dst ----------
// 16 lanes x uint4 per edge (256B row), 4 edges/inst group, 4x unroll.
// Packed v2f math (v_pk_* ops). No stats fusion (R9 post-mortem: 12.8M global
// atomics serialized — G12 violation).
__global__ __launch_bounds__(256) void k_agg(
    const int* __restrict__ rowptr, const int* __restrict__ col,
    const float* __restrict__ es, const float* __restrict__ ed,
    const unsigned* __restrict__ hb, const unsigned* __restrict__ linp,
    const float* __restrict__ lb, const float* __restrict__ gb,
    unsigned* __restrict__ xoutp, int N) {
  int lane = threadIdx.x & 63;
  int w = threadIdx.x >> 6;
  int d = blockIdx.x * 4 + w;
  if (d >= N) return;
  int start = rowptr[d], end = rowptr[d + 1];
  v2f edv = *(const v2f*)&ed[2 * d];
  int q = lane >> 4;   // edge quarter 0..3
  int m = lane & 15;   // feats 8m..8m+7
  int head_hi = m >= 8;
  v2f zero = {0.f, 0.f};
  v2f lk = {LEAKY, LEAKY};

  v2f acc[4] = {zero, zero, zero, zero};
  v2f sp = zero;
  int i = start;
  for (; i + 16 <= end; i += 16) {
#pragma unroll
    for (int b = 0; b < 4; ++b) {
      int idx = i + 4 * b + q;
      int s = col[idx];
      v2f ev = *(const v2f*)&es[2 * s];
      uint4 u = *(const uint4*)&hb[(size_t)s * 64 + m * 4];
      v2f e = ev + edv;
      v2f le = __builtin_elementwise_max(e, zero) + lk * __builtin_elementwise_min(e, zero);
      v2f p; p.x = __expf(le.x); p.y = __expf(le.y);
      sp += p;
      float f = head_hi ? p.y : p.x;
      v2f fv = {f, f};
      acc[0] = __builtin_elementwise_fma(fv, bpair(u.x), acc[0]);
      acc[1] = __builtin_elementwise_fma(fv, bpair(u.y), acc[1]);
      acc[2] = __builtin_elementwise_fma(fv, bpair(u.z), acc[2]);
      acc[3] = __builtin_elementwise_fma(fv, bpair(u.w), acc[3]);
    }
  }
  for (; i < end; i += 4) {  // masked tail, 4 edges/iter
    int idx = i + q;
    int valid = idx < end;
    int s = col[valid ? idx : end - 1];
    v2f ev = *(const v2f*)&es[2 * s];
    uint4 u = *(const uint4*)&hb[(size_t)s * 64 + m * 4];
    v2f e = ev + edv;
    v2f le = __builtin_elementwise_max(e, zero) + lk * __builtin_elementwise_min(e, zero);
    v2f p; p.x = __expf(le.x); p.y = __expf(le.y);
    if (!valid) p = zero;
    sp += p;
    float f = head_hi ? p.y : p.x;
    v2f fv = {f, f};
    acc[0] = __builtin_elementwise_fma(fv, bpair(u.x), acc[0]);
    acc[1] = __builtin_elementwise_fma(fv, bpair(u.y), acc[1]);
    acc[2] = __builtin_elementwise_fma(fv, bpair(u.z), acc[2]);
    acc[3] = __builtin_elementwise_fma(fv, bpair(u.w), acc[3]);
  }
  // reduce across quarters
#pragma unroll
  for (int k = 0; k < 4; ++k) {
    acc[k].x += __shfl_xor(acc[k].x, 16, 64);
    acc[k].x += __shfl_xor(acc[k].x, 32, 64);
    acc[k].y += __shfl_xor(acc[k].y, 16, 64);
    acc[k].y += __shfl_xor(acc[k].y, 32, 64);
  }
  sp.x += __shfl_xor(sp.x, 16, 64); sp.x += __shfl_xor(sp.x, 32, 64);
  sp.y += __shfl_xor(sp.y, 16, 64); sp.y += __shfl_xor(sp.y, 32, 64);

  if (q == 0) {
    float inv = 1.0f / (head_hi ? sp.y : sp.x);
    uint4 lv = *(const uint4*)&linp[(size_t)d * 64 + m * 4];
    int f8 = 8 * m;
    float4 lb0 = *(const float4*)&lb[f8], lb1 = *(const float4*)&lb[f8 + 4];
    float4 gb0 = *(const float4*)&gb[f8], gb1 = *(const float4*)&gb[f8 + 4];
    float v0 = blo(lv.x) + lb0.x + acc[0].x * inv + gb0.x;
    float v1 = bhi(lv.x) + lb0.y + acc[0].y * inv + gb0.y;
    float v2 = blo(lv.y) + lb0.z + acc[1].x * inv + gb0.z;
    float v3 = bhi(lv.y) + lb0.w + acc[1].y * inv + gb0.w;
    float v4 = blo(lv.z) + lb1.x + acc[2].x * inv + gb1.x;
    float v5 = bhi(lv.z) + lb1.y + acc[2].y * inv + gb1.y;
    float v6 = blo(lv.w) + lb1.z + acc[3].x * inv + gb1.z;
    float v7 = bhi(lv.w) + lb1.w + acc[3].y * inv + gb1.w;
    v0 = v0 > 0.f ? v0 : 0.f; v1 = v1 > 0.f ? v1 : 0.f;
    v2 = v2 > 0.f ? v2 : 0.f; v3 = v3 > 0.f ? v3 : 0.f;
    v4 = v4 > 0.f ? v4 : 0.f; v5 = v5 > 0.f ? v5 : 0.f;
    v6 = v6 > 0.f ? v6 : 0.f; v7 = v7 > 0.f ? v7 : 0.f;
    uint4 o;
    o.x = pack_bf16(v0, v1); o.y = pack_bf16(v2, v3);
    o.z = pack_bf16(v4, v5); o.w = pack_bf16(v6, v7);
    *(uint4*)&xoutp[(size_t)d * 64 + m * 4] = o;
  }
}

// ---------- layer 3: BN(inline, 8-replica stats) + tiny matmul + es/ed ----------
__global__ __launch_bounds__(256) void k_l3node(
    const unsigned* __restrict__ xp,
    const float* __restrict__ stats, const float* __restrict__ gamma, const float* __restrict__ beta,
    const float* __restrict__ W3, const float* __restrict__ LW3,
    const float* __restrict__ as3, const float* __restrict__ ad3,
    float* h3, float* lin3, float* es3, float* ed3, int N) {
  int lane = threadIdx.x & 63;
  int n = blockIdx.x * 4 + (threadIdx.x >> 6);
  if (n >= N) return;
  float inv_n = 1.0f / (float)N;
  int f0 = lane, f1 = 64 + lane;
  float su0 = 0.f, sq0 = 0.f, su1 = 0.f, sq1 = 0.f;
#pragma unroll
  for (int r = 0; r < 8; ++r) {
    su0 += stats[r * 256 + f0];  sq0 += stats[r * 256 + 128 + f0];
    su1 += stats[r * 256 + f1];  sq1 += stats[r * 256 + 128 + f1];
  }
  float mu0 = su0 * inv_n;
  float var0 = sq0 * inv_n - mu0 * mu0;
  float rs0 = rsqrtf(var0 + BN_EPS);
  float sc0 = gamma[f0] * rs0, sh0 = beta[f0] - mu0 * sc0;
  float mu1 = su1 * inv_n;
  float var1 = sq1 * inv_n - mu1 * mu1;
  float rs1 = rsqrtf(var1 + BN_EPS);
  float sc1 = gamma[f1] * rs1, sh1 = beta[f1] - mu1 * sc1;

  unsigned ua = xp[(size_t)n * 64 + (lane >> 1)];
  unsigned ub = xp[(size_t)n * 64 + 32 + (lane >> 1)];
  float xv0 = (lane & 1) ? bhi(ua) : blo(ua);
  float xv1 = (lane & 1) ? bhi(ub) : blo(ub);
  float xn0 = xv0 * sc0 + sh0;
  float xn1 = xv1 * sc1 + sh1;

  float2 w0 = *(const float2*)&W3[lane * 2];
  float2 w1 = *(const float2*)&W3[(64 + lane) * 2];
  float2 l0 = *(const float2*)&LW3[lane * 2];
  float2 l1 = *(const float2*)&LW3[(64 + lane) * 2];
  float hc0 = wsum(xn0 * w0.x + xn1 * w1.x);
  float hc1 = wsum(xn0 * w0.y + xn1 * w1.y);
  float lc0 = wsum(xn0 * l0.x + xn1 * l1.x);
  float lc1 = wsum(xn0 * l0.y + xn1 * l1.y);
  if (lane == 0) {
    h3[2 * n] = hc0; h3[2 * n + 1] = hc1;
    lin3[2 * n] = lc0; lin3[2 * n + 1] = lc1;
    es3[n] = hc0 * as3[0] + hc1 * as3[1];
    ed3[n] = hc0 * ad3[0] + hc1 * ad3[1];
  }
}

// ---------- layer 3 edge aggregation + final output ----------
__global__ __launch_bounds__(256) void k_agg3(
    const int* __restrict__ rowptr, const int* __restrict__ col,
    const float* __restrict__ es, const float* __restrict__ ed,
    const float* __restrict__ h3, const float* __restrict__ lin3,
    const float* __restrict__ lb3, const float* __restrict__ gb3,
    float* __restrict__ out, int N) {
  int lane = threadIdx.x & 63;
  int d = blockIdx.x * 4 + (threadIdx.x >> 6);
  if (d >= N) return;
  int start = rowptr[d], end = rowptr[d + 1];
  float edd = ed[d];
  float ps = 0.f, a0 = 0.f, a1 = 0.f;
  for (int i = start + lane; i < end; i += 64) {
    int s = col[i];
    float e = es[s] + edd; e = e > 0.f ? e : LEAKY * e;
    float p = __expf(e);
    float2 hv = *(const float2*)&h3[2 * s];
    ps += p; a0 += p * hv.x; a1 += p * hv.y;
  }
  ps = wsum(ps); a0 = wsum(a0); a1 = wsum(a1);
  if (lane < 2) {
    float a = (lane == 0 ? a0 : a1) / ps;
    float v = lin3[2 * d + lane] + lb3[lane] + a + gb3[lane];
    out[2 * d + lane] = v > 0.f ? v : 0.f;
  }
}

extern "C" void kernel_launch(void* const* d_in, const int* in_sizes, int n_in,
                              void* d_out, int out_size, void* d_ws, size_t ws_size,
                              hipStream_t stream) {
  const float* x   = (const float*)d_in[0];
  const void*  ei  = d_in[1];
  const float* W1  = (const float*)d_in[2];
  const float* as1 = (const float*)d_in[3];
  const float* ad1 = (const float*)d_in[4];
  const float* gb1 = (const float*)d_in[5];
  const float* lw1 = (const float*)d_in[6];
  const float* lb1 = (const float*)d_in[7];
  const float* bg1 = (const float*)d_in[8];
  const float* bb1 = (const float*)d_in[9];
  const float* W2  = (const float*)d_in[10];
  const float* as2 = (const float*)d_in[11];
  const float* ad2 = (const float*)d_in[12];
  const float* gb2 = (const float*)d_in[13];
  const float* lw2 = (const float*)d_in[14];
  const float* lb2 = (const float*)d_in[15];
  const float* bg2 = (const float*)d_in[16];
  const float* bb2 = (const float*)d_in[17];
  const float* W3  = (const float*)d_in[18];
  const float* as3 = (const float*)d_in[19];
  const float* ad3 = (const float*)d_in[20];
  const float* gb3 = (const float*)d_in[21];
  const float* lw3 = (const float*)d_in[22];
  const float* lb3 = (const float*)d_in[23];
  const float* bg3 = (const float*)d_in[24];
  const float* bb3 = (const float*)d_in[25];
  float* out = (float*)d_out;

  int N = in_sizes[0] / 128;
  int E = in_sizes[1] / 2;
  int M = E + N;
  int nb = (N + 255) >> 8;
  int nblk = (M + BCHUNK - 1) / BCHUNK;

  char* wsp = (char*)d_ws;
  size_t off = 0;
  auto alloc = [&](size_t bytes) -> void* {
    void* p = wsp + off;
    off = (off + bytes + 255) & ~(size_t)255;
    return p;
  };
  int* rowptr   = (int*)alloc(((size_t)N + 1) * 4);
  int* col      = (int*)alloc((size_t)M * 4);
  unsigned* tmp = (unsigned*)alloc((size_t)M * 4);
  int* counts   = (int*)alloc(((size_t)nb * nblk + 1) * 4);
  float* st1    = (float*)alloc(8 * 256 * 4);
  float* st2    = (float*)alloc(8 * 256 * 4);
  float* st3    = (float*)alloc(8 * 256 * 4);
  unsigned short* Bp1 = (unsigned short*)alloc(4096 * 16);
  unsigned short* Bp2 = (unsigned short*)alloc(4096 * 16);
  float4* Wesed1 = (float4*)alloc(128 * 16);
  float4* Wesed2 = (float4*)alloc(128 * 16);
  unsigned* hbp  = (unsigned*)alloc((size_t)N * 64 * 4);
  unsigned* linp = (unsigned*)alloc((size_t)N * 64 * 4);
  unsigned* x2p  = (unsigned*)alloc((size_t)N * 64 * 4);
  float* es    = (float*)alloc((size_t)N * 2 * 4);
  float* edb   = (float*)alloc((size_t)N * 2 * 4);
  float* h3    = (float*)alloc((size_t)N * 2 * 4);
  float* lin3  = (float*)alloc((size_t)N * 2 * 4);
  float* es3   = (float*)alloc((size_t)N * 4);
  float* ed3   = (float*)alloc((size_t)N * 4);
  (void)ws_size; (void)n_in; (void)out_size;

  hipMemsetAsync(st1, 0, 3 * 8 * 256 * 4, stream);  // st1,st2,st3 contiguous

  // CSR build (probe inlined into binA/binC)
  k_binA<<<nblk, 256, 0, stream>>>(ei, N, E, M, nb, nblk, counts);
  k_binScan<<<1, 1024, 0, stream>>>(counts, nb * nblk);
  k_binC<<<nblk, 256, 0, stream>>>(ei, N, E, M, nb, nblk, counts, tmp);
  k_binD<<<nb, 256, 0, stream>>>(tmp, counts, nb, nblk, M, N, rowptr, col);

  // combined weight prep + layer-1 BN stats
  k_prep<<<34 + 1024, 256, 0, stream>>>(W1, lw1, W2, lw2, as1, ad1, as2, ad2,
                                        x, N, Bp1, Bp2, Wesed1, Wesed2, st1);

  int gnode = (N + 3) / 4;
  int gmm = (N + 31) / 32;

  // ---- layer 1 ----
  k_mm<<<gmm, 256, 0, stream>>>(x, 0, st1, bg1, bb1, Bp1, Wesed1, hbp, linp, es, edb, N);
  k_agg<<<gnode, 256, 0, stream>>>(rowptr, col, es, edb, hbp, linp, lb1, gb1, x2p, N);

  // ---- layer 2 ----
  k_bnstats<<<1024, 128, 0, stream>>>(x2p, N, st2);
  k_mm<<<gmm, 256, 0, stream>>>(x2p, 1, st2, bg2, bb2, Bp2, Wesed2, hbp, linp, es, edb, N);
  k_agg<<<gnode, 256, 0, stream>>>(rowptr, col, es, edb, hbp, linp, lb2, gb2, x2p, N);

  // ---- layer 3 ----
  k_bnstats<<<1024, 128, 0, stream>>>(x2p, N, st3);
  k_l3node<<<gnode, 256, 0, stream>>>(x2p, st3, bg3, bb3, W3, lw3, as3, ad3,
                                      h3, lin3, es3, ed3, N);
  k_agg3<<<gnode, 256, 0, stream>>>(rowptr, col, es3, ed3, h3, lin3, lb3, gb3, out, N);
}

// Round 11
// 441.773 us; speedup vs baseline: 8.9925x; 1.0289x over previous
//
#include <hip/hip_runtime.h>

#define LEAKY 0.2f
#define BN_EPS 1e-5f
#define BCHUNK 8192

typedef __bf16 v8bf __attribute__((ext_vector_type(8)));
typedef float v16f __attribute__((ext_vector_type(16)));
typedef float v2f __attribute__((ext_vector_type(2)));

// ---------- wave helpers (wave64) ----------
__device__ __forceinline__ float wsum(float v) {
#pragma unroll
  for (int o = 32; o > 0; o >>= 1) v += __shfl_xor(v, o, 64);
  return v;
}

// packed-bf16: dword holds feat2j (low16) and feat2j+1 (high16)
__device__ __forceinline__ float blo(unsigned u) { return __uint_as_float(u << 16); }
__device__ __forceinline__ float bhi(unsigned u) { return __uint_as_float(u & 0xffff0000u); }
__device__ __forceinline__ v2f bpair(unsigned u) {
  v2f r; r.x = __uint_as_float(u << 16); r.y = __uint_as_float(u & 0xffff0000u); return r;
}
__device__ __forceinline__ unsigned pack_bf16(float a, float b) {
  unsigned ua = __float_as_uint(a), ub = __float_as_uint(b);
  ua = (ua + 0x7fffu + ((ua >> 16) & 1u)) >> 16;
  ub = (ub + 0x7fffu + ((ub >> 16) & 1u)) >> 16;
  return ua | (ub << 16);
}
__device__ __forceinline__ unsigned short bf16of(float a) {
  unsigned ua = __float_as_uint(a);
  return (unsigned short)((ua + 0x7fffu + ((ua >> 16) & 1u)) >> 16);
}

// edge_index may be int64 (reference dtype) or int32 (JAX x64 disabled).
__device__ __forceinline__ int edge_at(const void* ei, int is64, long long i) {
  return is64 ? (int)((const long long*)ei)[i] : ((const int*)ei)[i];
}

// ---------- CSR build: two-level counting sort (write-local) ----------
__global__ __launch_bounds__(256) void k_binA(const void* ei, int N, int E, int M,
                                              int nb, int nblk, int* counts) {
  __shared__ int hist[1024];
  __shared__ int sflag;
  int tid = threadIdx.x;
  if (tid < 64) {
    const long long* p = (const long long*)ei;
    long long v = p[tid];
    int bad = (v < 0 || v >= (long long)N) ? 1 : 0;
    unsigned long long mres = __ballot(bad);
    if (tid == 0) sflag = (mres == 0ull) ? 1 : 0;
  }
  for (int j = tid; j < nb; j += 256) hist[j] = 0;
  __syncthreads();
  int is64 = sflag;
  long long base = (long long)blockIdx.x * BCHUNK;
  int cnt = (int)min((long long)BCHUNK, (long long)M - base);
  for (int i = tid; i < cnt; i += 256) {
    long long g = base + i;
    int d = (g < E) ? edge_at(ei, is64, (long long)E + g) : (int)(g - E);
    atomicAdd(&hist[d >> 8], 1);
  }
  __syncthreads();
  for (int j = tid; j < nb; j += 256) counts[(size_t)j * nblk + blockIdx.x] = hist[j];
}

__global__ __launch_bounds__(1024) void k_binScan(int* counts, int total_entries) {
  __shared__ int part[1024];
  int tid = threadIdx.x;
  int per = (total_entries + 1023) / 1024;
  int lo = tid * per;
  int hi = lo + per; if (hi > total_entries) hi = total_entries;
  int s = 0;
  int i = lo;
  for (; i + 8 <= hi; i += 8) {
    int c0 = counts[i], c1 = counts[i + 1], c2 = counts[i + 2], c3 = counts[i + 3];
    int c4 = counts[i + 4], c5 = counts[i + 5], c6 = counts[i + 6], c7 = counts[i + 7];
    s += ((c0 + c1) + (c2 + c3)) + ((c4 + c5) + (c6 + c7));
  }
  for (; i < hi; ++i) s += counts[i];
  part[tid] = s;
  __syncthreads();
  for (int off = 1; off < 1024; off <<= 1) {
    int add = (tid >= off) ? part[tid - off] : 0;
    __syncthreads();
    part[tid] += add;
    __syncthreads();
  }
  int run = (tid == 0) ? 0 : part[tid - 1];
  i = lo;
  for (; i + 8 <= hi; i += 8) {
    int c0 = counts[i], c1 = counts[i + 1], c2 = counts[i + 2], c3 = counts[i + 3];
    int c4 = counts[i + 4], c5 = counts[i + 5], c6 = counts[i + 6], c7 = counts[i + 7];
    counts[i] = run; run += c0;
    counts[i + 1] = run; run += c1;
    counts[i + 2] = run; run += c2;
    counts[i + 3] = run; run += c3;
    counts[i + 4] = run; run += c4;
    counts[i + 5] = run; run += c5;
    counts[i + 6] = run; run += c6;
    counts[i + 7] = run; run += c7;
  }
  for (; i < hi; ++i) {
    int c = counts[i];
    counts[i] = run;
    run += c;
  }
}

__global__ __launch_bounds__(256) void k_binC(const void* ei, int N, int E, int M,
                                              int nb, int nblk, const int* counts, unsigned* tmp) {
  __shared__ int cur[1024];
  __shared__ int sflag;
  int tid = threadIdx.x;
  if (tid < 64) {
    const long long* p = (const long long*)ei;
    long long v = p[tid];
    int bad = (v < 0 || v >= (long long)N) ? 1 : 0;
    unsigned long long mres = __ballot(bad);
    if (tid == 0) sflag = (mres == 0ull) ? 1 : 0;
  }
  for (int j = tid; j < nb; j += 256) cur[j] = counts[(size_t)j * nblk + blockIdx.x];
  __syncthreads();
  int is64 = sflag;
  long long base = (long long)blockIdx.x * BCHUNK;
  int cnt = (int)min((long long)BCHUNK, (long long)M - base);
  for (int i = tid; i < cnt; i += 256) {
    long long g = base + i;
    int s, d;
    if (g < E) { s = edge_at(ei, is64, g); d = edge_at(ei, is64, (long long)E + g); }
    else       { s = d = (int)(g - E); }
    int pos = atomicAdd(&cur[d >> 8], 1);
    tmp[pos] = ((unsigned)s << 8) | (unsigned)(d & 255);
  }
}

__global__ __launch_bounds__(256) void k_binD(const unsigned* __restrict__ tmp,
                                              const int* __restrict__ counts,
                                              int nb, int nblk, int M, int N,
                                              int* __restrict__ rowptr, int* __restrict__ col) {
  __shared__ int scn[256];
  __shared__ int cur[256];
  int tid = threadIdx.x;
  int j = blockIdx.x;
  int base = counts[(size_t)j * nblk];
  int endv = (j + 1 < nb) ? counts[(size_t)(j + 1) * nblk] : M;
  int bc = endv - base;
  scn[tid] = 0;
  __syncthreads();
  for (int i = tid; i < bc; i += 256) atomicAdd(&scn[tmp[base + i] & 255], 1);
  __syncthreads();
  int v = scn[tid];
  __syncthreads();
  scn[tid] = v;
  __syncthreads();
  for (int off = 1; off < 256; off <<= 1) {
    int add = (tid >= off) ? scn[tid - off] : 0;
    __syncthreads();
    scn[tid] += add;
    __syncthreads();
  }
  int excl = scn[tid] - v;
  int d = (j << 8) + tid;
  if (d < N) rowptr[d] = base + excl;
  cur[tid] = base + excl;
  __syncthreads();
  for (int i = tid; i < bc; i += 256) {
    unsigned w = tmp[base + i];
    int pos = atomicAdd(&cur[w & 255], 1);
    col[pos] = (int)(w >> 8);
  }
  if (j == nb - 1 && tid == 0) rowptr[N] = M;
}

// ---------- BatchNorm stats for packed-bf16 input (layers 2/3) ----------
__global__ __launch_bounds__(128) void k_bnstats(const unsigned* __restrict__ xp,
                                                 int N, float* sums) {
  int f = threadIdx.x;
  int q = f >> 1, hi = f & 1;
  float s = 0.f, s2 = 0.f;
  for (int r = blockIdx.x; r < N; r += gridDim.x) {
    unsigned u = xp[(size_t)r * 64 + q];
    float v = hi ? bhi(u) : blo(u);
    s += v; s2 += v * v;
  }
  float* rep = sums + (size_t)(blockIdx.x & 7) * 256;
  atomicAdd(&rep[f], s);
  atomicAdd(&rep[128 + f], s2);
}

// ---------- combined prep ----------
// blocks 0-15: Bp1 tiles 0-7; 16-31: Bp2 tiles 0-7; 32/33: tile 8 (es/ed
// columns [W@as h0, W@as h1, W@ad h0, W@ad h1]) for Bp1/Bp2; 34..: layer-1
// BN stats of fp32 x into 8-replica slots.
__global__ __launch_bounds__(256) void k_prep(
    const float* __restrict__ W1, const float* __restrict__ LW1,
    const float* __restrict__ W2, const float* __restrict__ LW2,
    const float* __restrict__ as1, const float* __restrict__ ad1,
    const float* __restrict__ as2, const float* __restrict__ ad2,
    const float* __restrict__ x, int N,
    unsigned short* __restrict__ Bp1, unsigned short* __restrict__ Bp2,
    float* __restrict__ stats1) {
  int blk = blockIdx.x;
  int tid = threadIdx.x;
  if (blk >= 34) {
    int b = blk - 34;  // 0..1023
    int f = tid & 127;
    int half = tid >> 7;
    float s = 0.f, s2 = 0.f;
    for (int r = b + half * 1024; r < N; r += 2048) {
      float v = x[(size_t)r * 128 + f];
      s += v; s2 += v * v;
    }
    float* rep = stats1 + (size_t)(b & 7) * 256;
    atomicAdd(&rep[f], s);
    atomicAdd(&rep[128 + f], s2);
    return;
  }
  if (blk >= 32) {
    // tile 8: es/ed columns in B-fragment order
    __shared__ float wes[128][4];
    const float* W = (blk == 32) ? W1 : W2;
    const float* as_ = (blk == 32) ? as1 : as2;
    const float* ad_ = (blk == 32) ? ad1 : ad2;
    unsigned short* Bp = (blk == 32) ? Bp1 : Bp2;
#pragma unroll
    for (int it = 0; it < 2; ++it) {
      int k = tid & 127;
      int c = (tid >> 7) + 2 * it;  // 0,1 then 2,3
      const float* a = (c < 2) ? as_ : ad_;
      int hb2 = (c & 1) * 64;
      float sum = 0.f;
      for (int f = 0; f < 64; ++f) sum += W[k * 128 + hb2 + f] * a[hb2 + f];
      wes[k][c] = sum;
    }
    __syncthreads();
    for (int fr = tid; fr < 512; fr += 256) {
      int lane = fr & 63, s = fr >> 6;
      int n = lane & 31;
      int k0 = s * 16 + (lane >> 5) * 8;
      unsigned short tb[8];
#pragma unroll
      for (int j = 0; j < 8; ++j)
        tb[j] = bf16of((n < 4) ? wes[k0 + j][n] : 0.f);
      uint4 pk;
      pk.x = (unsigned)tb[0] | ((unsigned)tb[1] << 16);
      pk.y = (unsigned)tb[2] | ((unsigned)tb[3] << 16);
      pk.z = (unsigned)tb[4] | ((unsigned)tb[5] << 16);
      pk.w = (unsigned)tb[6] | ((unsigned)tb[7] << 16);
      int fi = (64 + s) * 64 + lane;  // tile 8
      *(uint4*)&Bp[(size_t)fi * 8] = pk;
    }
    return;
  }
  const float* W  = (blk < 16) ? W1 : W2;
  const float* LW = (blk < 16) ? LW1 : LW2;
  unsigned short* Bp = (blk < 16) ? Bp1 : Bp2;
  int fi = (blk & 15) * 256 + tid;  // 4096 frags (tiles 0-7)
  int lane = fi & 63, s = (fi >> 6) & 7, t = fi >> 9;
  int n = t * 32 + (lane & 31);
  int k0 = s * 16 + (lane >> 5) * 8;
  unsigned short tb[8];
#pragma unroll
  for (int j = 0; j < 8; ++j) {
    int k = k0 + j;
    float v = (n < 128) ? W[k * 128 + n] : LW[k * 128 + (n - 128)];
    tb[j] = bf16of(v);
  }
  uint4 pk;
  pk.x = (unsigned)tb[0] | ((unsigned)tb[1] << 16);
  pk.y = (unsigned)tb[2] | ((unsigned)tb[3] << 16);
  pk.z = (unsigned)tb[4] | ((unsigned)tb[5] << 16);
  pk.w = (unsigned)tb[6] | ((unsigned)tb[7] << 16);
  *(uint4*)&Bp[(size_t)fi * 8] = pk;
}

// ---------- MFMA matmul; es/ed via 9th B-tile MFMA (wave 0) ----------
__global__ __launch_bounds__(256) void k_mm(
    const void* __restrict__ xin, int packed,
    const float* __restrict__ stats, const float* __restrict__ gamma, const float* __restrict__ beta,
    const unsigned short* __restrict__ Bp,
    unsigned* __restrict__ hb, unsigned* __restrict__ linp,
    float* __restrict__ es, float* __restrict__ ed, int N) {
  __shared__ __align__(16) unsigned short Al[32 * 136];
  __shared__ float scl_s[128], sht_s[128];
  int tid = threadIdx.x;
  int lane = tid & 63;
  int w = tid >> 6;
  int rowBase = blockIdx.x * 32;

  if (tid < 128) {
    float s = 0.f, s2 = 0.f;
#pragma unroll
    for (int r = 0; r < 8; ++r) {
      s += stats[r * 256 + tid];
      s2 += stats[r * 256 + 128 + tid];
    }
    float inv_n = 1.0f / (float)N;
    float mu = s * inv_n;
    float var = s2 * inv_n - mu * mu;
    float rs = rsqrtf(var + BN_EPS);
    float sc = gamma[tid] * rs;
    scl_s[tid] = sc;
    sht_s[tid] = beta[tid] - mu * sc;
  }

  v8bf bfrag[2][8];
#pragma unroll
  for (int t = 0; t < 2; ++t)
#pragma unroll
    for (int s = 0; s < 8; ++s) {
      int fi = ((2 * w + t) * 8 + s) * 64 + lane;
      bfrag[t][s] = *(const v8bf*)&Bp[(size_t)fi * 8];
    }
  __syncthreads();

  if (!packed) {
    const float* x = (const float*)xin;
    for (int q = tid; q < 32 * 32; q += 256) {
      int r = q >> 5, k4 = (q & 31) * 4;
      int row = rowBase + r;
      float4 v = make_float4(0.f, 0.f, 0.f, 0.f);
      if (row < N) v = *(const float4*)&x[(size_t)row * 128 + k4];
      unsigned p0 = pack_bf16(v.x * scl_s[k4] + sht_s[k4], v.y * scl_s[k4 + 1] + sht_s[k4 + 1]);
      unsigned p1 = pack_bf16(v.z * scl_s[k4 + 2] + sht_s[k4 + 2], v.w * scl_s[k4 + 3] + sht_s[k4 + 3]);
      *(uint2*)&Al[r * 136 + k4] = make_uint2(p0, p1);
    }
  } else {
    const unsigned* xp = (const unsigned*)xin;
    for (int q = tid; q < 32 * 16; q += 256) {
      int r = q >> 4, g = q & 15;
      int row = rowBase + r;
      uint4 u = make_uint4(0u, 0u, 0u, 0u);
      if (row < N) u = *(const uint4*)&xp[(size_t)row * 64 + g * 4];
      int f = g * 8;
      uint4 o;
      o.x = pack_bf16(blo(u.x) * scl_s[f] + sht_s[f], bhi(u.x) * scl_s[f + 1] + sht_s[f + 1]);
      o.y = pack_bf16(blo(u.y) * scl_s[f + 2] + sht_s[f + 2], bhi(u.y) * scl_s[f + 3] + sht_s[f + 3]);
      o.z = pack_bf16(blo(u.z) * scl_s[f + 4] + sht_s[f + 4], bhi(u.z) * scl_s[f + 5] + sht_s[f + 5]);
      o.w = pack_bf16(blo(u.w) * scl_s[f + 6] + sht_s[f + 6], bhi(u.w) * scl_s[f + 7] + sht_s[f + 7]);
      *(uint4*)&Al[r * 136 + f] = o;
    }
  }
  __syncthreads();

  int m = lane & 31, half = lane >> 5;
  v8bf afrag[8];
#pragma unroll
  for (int s = 0; s < 8; ++s)
    afrag[s] = *(const v8bf*)&Al[m * 136 + s * 16 + half * 8];

  v16f acc0 = {}, acc1 = {};
#pragma unroll
  for (int s = 0; s < 8; ++s) {
    acc0 = __builtin_amdgcn_mfma_f32_32x32x16_bf16(afrag[s], bfrag[0][s], acc0, 0, 0, 0);
    acc1 = __builtin_amdgcn_mfma_f32_32x32x16_bf16(afrag[s], bfrag[1][s], acc1, 0, 0, 0);
  }

  // es/ed via tile 8 (cols 0..3), wave 0 only (all waves share the A tile)
  v16f acc2 = {};
  if (w == 0) {
#pragma unroll
    for (int s = 0; s < 8; ++s) {
      v8bf besf = *(const v8bf*)&Bp[(size_t)((64 + s) * 64 + lane) * 8];
      acc2 = __builtin_amdgcn_mfma_f32_32x32x16_bf16(afrag[s], besf, acc2, 0, 0, 0);
    }
  }

  int mlo = half * 4;
  int t0 = 2 * w, t1 = 2 * w + 1;
#pragma unroll
  for (int r = 0; r < 16; ++r) {
    int row = (r & 3) + 8 * (r >> 2) + mlo;
    int node = rowBase + row;
    float a0 = acc0[r], a1 = acc1[r];
    float b0 = __shfl_xor(a0, 1, 64);
    float b1 = __shfl_xor(a1, 1, 64);
    if (node < N && !(lane & 1)) {
      if (t0 < 4) {
        hb[(size_t)node * 64 + (t0 * 16 + (m >> 1))] = pack_bf16(a0, b0);
        hb[(size_t)node * 64 + (t1 * 16 + (m >> 1))] = pack_bf16(a1, b1);
      } else {
        linp[(size_t)node * 64 + ((t0 - 4) * 16 + (m >> 1))] = pack_bf16(a0, b0);
        linp[(size_t)node * 64 + ((t1 - 4) * 16 + (m >> 1))] = pack_bf16(a1, b1);
      }
    }
    if (w == 0 && m < 4 && node < N) {
      float v = acc2[r];
      if (m < 2) es[2 * node + (m & 1)] = v;
      else       ed[2 * node + (m & 1)] = v;
    }
  }
}

// ---------- single-pass edge aggregation + combine; one wave per dst ----------
__global__ __launch_bounds__(256) void k_agg(
    const int* __restrict__ rowptr, const int* __restrict__ col,
    const float* __restrict__ es, const float* __restrict__ ed,
    const unsigned* __restrict__ hb, const unsigned* __restrict__ linp,
    const float* __restrict__ lb, const float* __restrict__ gb,
    unsigned* __restrict__ xoutp, int N) {
  int lane = threadIdx.x & 63;
  int w = threadIdx.x >> 6;
  int d = blockIdx.x * 4 + w;
  if (d >= N) return;
  int start = rowptr[d], end = rowptr[d + 1];
  v2f edv = *(const v2f*)&ed[2 * d];
  int q = lane >> 4;   // edge quarter 0..3
  int m = lane & 15;   // feats 8m..8m+7
  int head_hi = m >= 8;
  v2f zero = {0.f, 0.f};
  v2f lk = {LEAKY, LEAKY};

  v2f acc[4] = {zero, zero, zero, zero};
  v2f sp = zero;
  int i = start;
  for (; i + 16 <= end; i += 16) {
#pragma unroll
    for (int b = 0; b < 4; ++b) {
      int idx = i + 4 * b + q;
      int s = col[idx];
      v2f ev = *(const v2f*)&es[2 * s];
      uint4 u = *(const uint4*)&hb[(size_t)s * 64 + m * 4];
      v2f e = ev + edv;
      v2f le = __builtin_elementwise_max(e, zero) + lk * __builtin_elementwise_min(e, zero);
      v2f p; p.x = __expf(le.x); p.y = __expf(le.y);
      sp += p;
      float f = head_hi ? p.y : p.x;
      v2f fv = {f, f};
      acc[0] = __builtin_elementwise_fma(fv, bpair(u.x), acc[0]);
      acc[1] = __builtin_elementwise_fma(fv, bpair(u.y), acc[1]);
      acc[2] = __builtin_elementwise_fma(fv, bpair(u.z), acc[2]);
      acc[3] = __builtin_elementwise_fma(fv, bpair(u.w), acc[3]);
    }
  }
  for (; i < end; i += 4) {  // masked tail, 4 edges/iter
    int idx = i + q;
    int valid = idx < end;
    int s = col[valid ? idx : end - 1];
    v2f ev = *(const v2f*)&es[2 * s];
    uint4 u = *(const uint4*)&hb[(size_t)s * 64 + m * 4];
    v2f e = ev + edv;
    v2f le = __builtin_elementwise_max(e, zero) + lk * __builtin_elementwise_min(e, zero);
    v2f p; p.x = __expf(le.x); p.y = __expf(le.y);
    if (!valid) p = zero;
    sp += p;
    float f = head_hi ? p.y : p.x;
    v2f fv = {f, f};
    acc[0] = __builtin_elementwise_fma(fv, bpair(u.x), acc[0]);
    acc[1] = __builtin_elementwise_fma(fv, bpair(u.y), acc[1]);
    acc[2] = __builtin_elementwise_fma(fv, bpair(u.z), acc[2]);
    acc[3] = __builtin_elementwise_fma(fv, bpair(u.w), acc[3]);
  }
  // reduce across quarters
#pragma unroll
  for (int k = 0; k < 4; ++k) {
    acc[k].x += __shfl_xor(acc[k].x, 16, 64);
    acc[k].x += __shfl_xor(acc[k].x, 32, 64);
    acc[k].y += __shfl_xor(acc[k].y, 16, 64);
    acc[k].y += __shfl_xor(acc[k].y, 32, 64);
  }
  sp.x += __shfl_xor(sp.x, 16, 64); sp.x += __shfl_xor(sp.x, 32, 64);
  sp.y += __shfl_xor(sp.y, 16, 64); sp.y += __shfl_xor(sp.y, 32, 64);

  if (q == 0) {
    float inv = 1.0f / (head_hi ? sp.y : sp.x);
    uint4 lv = *(const uint4*)&linp[(size_t)d * 64 + m * 4];
    int f8 = 8 * m;
    float4 lb0 = *(const float4*)&lb[f8], lb1 = *(const float4*)&lb[f8 + 4];
    float4 gb0 = *(const float4*)&gb[f8], gb1 = *(const float4*)&gb[f8 + 4];
    float v0 = blo(lv.x) + lb0.x + acc[0].x * inv + gb0.x;
    float v1 = bhi(lv.x) + lb0.y + acc[0].y * inv + gb0.y;
    float v2 = blo(lv.y) + lb0.z + acc[1].x * inv + gb0.z;
    float v3 = bhi(lv.y) + lb0.w + acc[1].y * inv + gb0.w;
    float v4 = blo(lv.z) + lb1.x + acc[2].x * inv + gb1.x;
    float v5 = bhi(lv.z) + lb1.y + acc[2].y * inv + gb1.y;
    float v6 = blo(lv.w) + lb1.z + acc[3].x * inv + gb1.z;
    float v7 = bhi(lv.w) + lb1.w + acc[3].y * inv + gb1.w;
    v0 = v0 > 0.f ? v0 : 0.f; v1 = v1 > 0.f ? v1 : 0.f;
    v2 = v2 > 0.f ? v2 : 0.f; v3 = v3 > 0.f ? v3 : 0.f;
    v4 = v4 > 0.f ? v4 : 0.f; v5 = v5 > 0.f ? v5 : 0.f;
    v6 = v6 > 0.f ? v6 : 0.f; v7 = v7 > 0.f ? v7 : 0.f;
    uint4 o;
    o.x = pack_bf16(v0, v1); o.y = pack_bf16(v2, v3);
    o.z = pack_bf16(v4, v5); o.w = pack_bf16(v6, v7);
    *(uint4*)&xoutp[(size_t)d * 64 + m * 4] = o;
  }
}

// ---------- layer 3: BN(inline, 8-replica stats) + tiny matmul + es/ed ----------
__global__ __launch_bounds__(256) void k_l3node(
    const unsigned* __restrict__ xp,
    const float* __restrict__ stats, const float* __restrict__ gamma, const float* __restrict__ beta,
    const float* __restrict__ W3, const float* __restrict__ LW3,
    const float* __restrict__ as3, const float* __restrict__ ad3,
    float* h3, float* lin3, float* es3, float* ed3, int N) {
  int lane = threadIdx.x & 63;
  int n = blockIdx.x * 4 + (threadIdx.x >> 6);
  if (n >= N) return;
  float inv_n = 1.0f / (float)N;
  int f0 = lane, f1 = 64 + lane;
  float su0 = 0.f, sq0 = 0.f, su1 = 0.f, sq1 = 0.f;
#pragma unroll
  for (int r = 0; r < 8; ++r) {
    su0 += stats[r * 256 + f0];  sq0 += stats[r * 256 + 128 + f0];
    su1 += stats[r * 256 + f1];  sq1 += stats[r * 256 + 128 + f1];
  }
  float mu0 = su0 * inv_n;
  float var0 = sq0 * inv_n - mu0 * mu0;
  float rs0 = rsqrtf(var0 + BN_EPS);
  float sc0 = gamma[f0] * rs0, sh0 = beta[f0] - mu0 * sc0;
  float mu1 = su1 * inv_n;
  float var1 = sq1 * inv_n - mu1 * mu1;
  float rs1 = rsqrtf(var1 + BN_EPS);
  float sc1 = gamma[f1] * rs1, sh1 = beta[f1] - mu1 * sc1;

  unsigned ua = xp[(size_t)n * 64 + (lane >> 1)];
  unsigned ub = xp[(size_t)n * 64 + 32 + (lane >> 1)];
  float xv0 = (lane & 1) ? bhi(ua) : blo(ua);
  float xv1 = (lane & 1) ? bhi(ub) : blo(ub);
  float xn0 = xv0 * sc0 + sh0;
  float xn1 = xv1 * sc1 + sh1;

  float2 w0 = *(const float2*)&W3[lane * 2];
  float2 w1 = *(const float2*)&W3[(64 + lane) * 2];
  float2 l0 = *(const float2*)&LW3[lane * 2];
  float2 l1 = *(const float2*)&LW3[(64 + lane) * 2];
  float hc0 = wsum(xn0 * w0.x + xn1 * w1.x);
  float hc1 = wsum(xn0 * w0.y + xn1 * w1.y);
  float lc0 = wsum(xn0 * l0.x + xn1 * l1.x);
  float lc1 = wsum(xn0 * l0.y + xn1 * l1.y);
  if (lane == 0) {
    h3[2 * n] = hc0; h3[2 * n + 1] = hc1;
    lin3[2 * n] = lc0; lin3[2 * n + 1] = lc1;
    es3[n] = hc0 * as3[0] + hc1 * as3[1];
    ed3[n] = hc0 * ad3[0] + hc1 * ad3[1];
  }
}

// ---------- layer 3 edge aggregation + final output ----------
__global__ __launch_bounds__(256) void k_agg3(
    const int* __restrict__ rowptr, const int* __restrict__ col,
    const float* __restrict__ es, const float* __restrict__ ed,
    const float* __restrict__ h3, const float* __restrict__ lin3,
    const float* __restrict__ lb3, const float* __restrict__ gb3,
    float* __restrict__ out, int N) {
  int lane = threadIdx.x & 63;
  int d = blockIdx.x * 4 + (threadIdx.x >> 6);
  if (d >= N) return;
  int start = rowptr[d], end = rowptr[d + 1];
  float edd = ed[d];
  float ps = 0.f, a0 = 0.f, a1 = 0.f;
  for (int i = start + lane; i < end; i += 64) {
    int s = col[i];
    float e = es[s] + edd; e = e > 0.f ? e : LEAKY * e;
    float p = __expf(e);
    float2 hv = *(const float2*)&h3[2 * s];
    ps += p; a0 += p * hv.x; a1 += p * hv.y;
  }
  ps = wsum(ps); a0 = wsum(a0); a1 = wsum(a1);
  if (lane < 2) {
    float a = (lane == 0 ? a0 : a1) / ps;
    float v = lin3[2 * d + lane] + lb3[lane] + a + gb3[lane];
    out[2 * d + lane] = v > 0.f ? v : 0.f;
  }
}

extern "C" void kernel_launch(void* const* d_in, const int* in_sizes, int n_in,
                              void* d_out, int out_size, void* d_ws, size_t ws_size,
                              hipStream_t stream) {
  const float* x   = (const float*)d_in[0];
  const void*  ei  = d_in[1];
  const float* W1  = (const float*)d_in[2];
  const float* as1 = (const float*)d_in[3];
  const float* ad1 = (const float*)d_in[4];
  const float* gb1 = (const float*)d_in[5];
  const float* lw1 = (const float*)d_in[6];
  const float* lb1 = (const float*)d_in[7];
  const float* bg1 = (const float*)d_in[8];
  const float* bb1 = (const float*)d_in[9];
  const float* W2  = (const float*)d_in[10];
  const float* as2 = (const float*)d_in[11];
  const float* ad2 = (const float*)d_in[12];
  const float* gb2 = (const float*)d_in[13];
  const float* lw2 = (const float*)d_in[14];
  const float* lb2 = (const float*)d_in[15];
  const float* bg2 = (const float*)d_in[16];
  const float* bb2 = (const float*)d_in[17];
  const float* W3  = (const float*)d_in[18];
  const float* as3 = (const float*)d_in[19];
  const float* ad3 = (const float*)d_in[20];
  const float* gb3 = (const float*)d_in[21];
  const float* lw3 = (const float*)d_in[22];
  const float* lb3 = (const float*)d_in[23];
  const float* bg3 = (const float*)d_in[24];
  const float* bb3 = (const float*)d_in[25];
  float* out = (float*)d_out;

  int N = in_sizes[0] / 128;
  int E = in_sizes[1] / 2;
  int M = E + N;
  int nb = (N + 255) >> 8;
  int nblk = (M + BCHUNK - 1) / BCHUNK;

  char* wsp = (char*)d_ws;
  size_t off = 0;
  auto alloc = [&](size_t bytes) -> void* {
    void* p = wsp + off;
    off = (off + bytes + 255) & ~(size_t)255;
    return p;
  };
  int* rowptr   = (int*)alloc(((size_t)N + 1) * 4);
  int* col      = (int*)alloc((size_t)M * 4);
  unsigned* tmp = (unsigned*)alloc((size_t)M * 4);
  int* counts   = (int*)alloc(((size_t)nb * nblk + 1) * 4);
  float* st1    = (float*)alloc(8 * 256 * 4);
  float* st2    = (float*)alloc(8 * 256 * 4);
  float* st3    = (float*)alloc(8 * 256 * 4);
  unsigned short* Bp1 = (unsigned short*)alloc(4608 * 16);  // 9 tiles
  unsigned short* Bp2 = (unsigned short*)alloc(4608 * 16);
  unsigned* hbp  = (unsigned*)alloc((size_t)N * 64 * 4);
  unsigned* linp = (unsigned*)alloc((size_t)N * 64 * 4);
  unsigned* x2p  = (unsigned*)alloc((size_t)N * 64 * 4);
  float* es    = (float*)alloc((size_t)N * 2 * 4);
  float* edb   = (float*)alloc((size_t)N * 2 * 4);
  float* h3    = (float*)alloc((size_t)N * 2 * 4);
  float* lin3  = (float*)alloc((size_t)N * 2 * 4);
  float* es3   = (float*)alloc((size_t)N * 4);
  float* ed3   = (float*)alloc((size_t)N * 4);
  (void)ws_size; (void)n_in; (void)out_size;

  hipMemsetAsync(st1, 0, 3 * 8 * 256 * 4, stream);  // st1,st2,st3 contiguous

  // CSR build (probe inlined into binA/binC)
  k_binA<<<nblk, 256, 0, stream>>>(ei, N, E, M, nb, nblk, counts);
  k_binScan<<<1, 1024, 0, stream>>>(counts, nb * nblk);
  k_binC<<<nblk, 256, 0, stream>>>(ei, N, E, M, nb, nblk, counts, tmp);
  k_binD<<<nb, 256, 0, stream>>>(tmp, counts, nb, nblk, M, N, rowptr, col);

  // combined weight prep (incl. tile-8 es/ed columns) + layer-1 BN stats
  k_prep<<<34 + 1024, 256, 0, stream>>>(W1, lw1, W2, lw2, as1, ad1, as2, ad2,
                                        x, N, Bp1, Bp2, st1);

  int gnode = (N + 3) / 4;
  int gmm = (N + 31) / 32;

  // ---- layer 1 ----
  k_mm<<<gmm, 256, 0, stream>>>(x, 0, st1, bg1, bb1, Bp1, hbp, linp, es, edb, N);
  k_agg<<<gnode, 256, 0, stream>>>(rowptr, col, es, edb, hbp, linp, lb1, gb1, x2p, N);

  // ---- layer 2 ----
  k_bnstats<<<1024, 128, 0, stream>>>(x2p, N, st2);
  k_mm<<<gmm, 256, 0, stream>>>(x2p, 1, st2, bg2, bb2, Bp2, hbp, linp, es, edb, N);
  k_agg<<<gnode, 256, 0, stream>>>(rowptr, col, es, edb, hbp, linp, lb2, gb2, x2p, N);

  // ---- layer 3 ----
  k_bnstats<<<1024, 128, 0, stream>>>(x2p, N, st3);
  k_l3node<<<gnode, 256, 0, stream>>>(x2p, st3, bg3, bb3, W3, lw3, as3, ad3,
                                      h3, lin3, es3, ed3, N);
  k_agg3<<<gnode, 256, 0, stream>>>(rowptr, col, es3, ed3, h3, lin3, lb3, gb3, out, N);
}

// Round 12
// 433.593 us; speedup vs baseline: 9.1621x; 1.0189x over previous
//
#include <hip/hip_runtime.h>

#define LEAKY 0.2f
#define BN_EPS 1e-5f
#define BCHUNK 8192

typedef __bf16 v8bf __attribute__((ext_vector_type(8)));
typedef float v16f __attribute__((ext_vector_type(16)));
typedef float v2f __attribute__((ext_vector_type(2)));

// ---------- wave helpers (wave64) ----------
__device__ __forceinline__ float wsum(float v) {
#pragma unroll
  for (int o = 32; o > 0; o >>= 1) v += __shfl_xor(v, o, 64);
  return v;
}

// packed-bf16: dword holds feat2j (low16) and feat2j+1 (high16)
__device__ __forceinline__ float blo(unsigned u) { return __uint_as_float(u << 16); }
__device__ __forceinline__ float bhi(unsigned u) { return __uint_as_float(u & 0xffff0000u); }
__device__ __forceinline__ v2f bpair(unsigned u) {
  v2f r; r.x = __uint_as_float(u << 16); r.y = __uint_as_float(u & 0xffff0000u); return r;
}
__device__ __forceinline__ unsigned pack_bf16(float a, float b) {
  unsigned ua = __float_as_uint(a), ub = __float_as_uint(b);
  ua = (ua + 0x7fffu + ((ua >> 16) & 1u)) >> 16;
  ub = (ub + 0x7fffu + ((ub >> 16) & 1u)) >> 16;
  return ua | (ub << 16);
}
__device__ __forceinline__ unsigned short bf16of(float a) {
  unsigned ua = __float_as_uint(a);
  return (unsigned short)((ua + 0x7fffu + ((ua >> 16) & 1u)) >> 16);
}

// edge_index may be int64 (reference dtype) or int32 (JAX x64 disabled).
__device__ __forceinline__ int edge_at(const void* ei, int is64, long long i) {
  return is64 ? (int)((const long long*)ei)[i] : ((const int*)ei)[i];
}

// =================== device bodies (shared by merged kernels) ===================

// binA: per-chunk bucket histogram (bucket = dst>>7). lds: >=1025 ints.
__device__ __forceinline__ void binA_body(int blk, const void* ei, int N, int E, int M,
                                          int nb, int nblk, int* counts, int* lds) {
  int* hist = lds;
  int* sflag = lds + 1024;
  int tid = threadIdx.x;
  if (tid < 64) {
    const long long* p = (const long long*)ei;
    long long v = p[tid];
    int bad = (v < 0 || v >= (long long)N) ? 1 : 0;
    unsigned long long mres = __ballot(bad);
    if (tid == 0) *sflag = (mres == 0ull) ? 1 : 0;
  }
  for (int j = tid; j < nb; j += 256) hist[j] = 0;
  __syncthreads();
  int is64 = *sflag;
  long long base = (long long)blk * BCHUNK;
  int cnt = (int)min((long long)BCHUNK, (long long)M - base);
  for (int i = tid; i < cnt; i += 256) {
    long long g = base + i;
    int d = (g < E) ? edge_at(ei, is64, (long long)E + g) : (int)(g - E);
    atomicAdd(&hist[d >> 7], 1);
  }
  __syncthreads();
  for (int j = tid; j < nb; j += 256) counts[(size_t)j * nblk + blk] = hist[j];
}

// binC: scatter packed (src<<7 | dst&127) into bucket-partitioned tmp.
__device__ __forceinline__ void binC_body(int blk, const void* ei, int N, int E, int M,
                                          int nb, int nblk, const int* counts,
                                          unsigned* tmp, int* lds) {
  int* cur = lds;
  int* sflag = lds + 1024;
  int tid = threadIdx.x;
  if (tid < 64) {
    const long long* p = (const long long*)ei;
    long long v = p[tid];
    int bad = (v < 0 || v >= (long long)N) ? 1 : 0;
    unsigned long long mres = __ballot(bad);
    if (tid == 0) *sflag = (mres == 0ull) ? 1 : 0;
  }
  for (int j = tid; j < nb; j += 256) cur[j] = counts[(size_t)j * nblk + blk];
  __syncthreads();
  int is64 = *sflag;
  long long base = (long long)blk * BCHUNK;
  int cnt = (int)min((long long)BCHUNK, (long long)M - base);
  for (int i = tid; i < cnt; i += 256) {
    long long g = base + i;
    int s, d;
    if (g < E) { s = edge_at(ei, is64, g); d = edge_at(ei, is64, (long long)E + g); }
    else       { s = d = (int)(g - E); }
    int pos = atomicAdd(&cur[d >> 7], 1);
    tmp[pos] = ((unsigned)s << 7) | (unsigned)(d & 127);
  }
}

#define MM_SMEM (32 * 136 * 2 + 128 * 4 + 128 * 4)  // Al + scl + sht = 9728 B

// MFMA matmul + es/ed via 9th B-tile (wave 0). smem: MM_SMEM bytes, 16-aligned.
__device__ __forceinline__ void mm_body(int blk, const void* xin, int packed,
    const float* stats, const float* gamma, const float* beta,
    const unsigned short* Bp, unsigned* hb, unsigned* linp,
    float* es, float* ed, int N, char* smem) {
  unsigned short* Al = (unsigned short*)smem;                  // 32*136
  float* scl_s = (float*)(smem + 8704);
  float* sht_s = (float*)(smem + 8704 + 512);
  int tid = threadIdx.x;
  int lane = tid & 63;
  int w = tid >> 6;
  int rowBase = blk * 32;

  if (tid < 128) {
    float s = 0.f, s2 = 0.f;
#pragma unroll
    for (int r = 0; r < 8; ++r) {
      s += stats[r * 256 + tid];
      s2 += stats[r * 256 + 128 + tid];
    }
    float inv_n = 1.0f / (float)N;
    float mu = s * inv_n;
    float var = s2 * inv_n - mu * mu;
    float rs = rsqrtf(var + BN_EPS);
    float sc = gamma[tid] * rs;
    scl_s[tid] = sc;
    sht_s[tid] = beta[tid] - mu * sc;
  }

  v8bf bfrag[2][8];
#pragma unroll
  for (int t = 0; t < 2; ++t)
#pragma unroll
    for (int s = 0; s < 8; ++s) {
      int fi = ((2 * w + t) * 8 + s) * 64 + lane;
      bfrag[t][s] = *(const v8bf*)&Bp[(size_t)fi * 8];
    }
  __syncthreads();

  if (!packed) {
    const float* x = (const float*)xin;
    for (int q = tid; q < 32 * 32; q += 256) {
      int r = q >> 5, k4 = (q & 31) * 4;
      int row = rowBase + r;
      float4 v = make_float4(0.f, 0.f, 0.f, 0.f);
      if (row < N) v = *(const float4*)&x[(size_t)row * 128 + k4];
      unsigned p0 = pack_bf16(v.x * scl_s[k4] + sht_s[k4], v.y * scl_s[k4 + 1] + sht_s[k4 + 1]);
      unsigned p1 = pack_bf16(v.z * scl_s[k4 + 2] + sht_s[k4 + 2], v.w * scl_s[k4 + 3] + sht_s[k4 + 3]);
      *(uint2*)&Al[r * 136 + k4] = make_uint2(p0, p1);
    }
  } else {
    const unsigned* xp = (const unsigned*)xin;
    for (int q = tid; q < 32 * 16; q += 256) {
      int r = q >> 4, g = q & 15;
      int row = rowBase + r;
      uint4 u = make_uint4(0u, 0u, 0u, 0u);
      if (row < N) u = *(const uint4*)&xp[(size_t)row * 64 + g * 4];
      int f = g * 8;
      uint4 o;
      o.x = pack_bf16(blo(u.x) * scl_s[f] + sht_s[f], bhi(u.x) * scl_s[f + 1] + sht_s[f + 1]);
      o.y = pack_bf16(blo(u.y) * scl_s[f + 2] + sht_s[f + 2], bhi(u.y) * scl_s[f + 3] + sht_s[f + 3]);
      o.z = pack_bf16(blo(u.z) * scl_s[f + 4] + sht_s[f + 4], bhi(u.z) * scl_s[f + 5] + sht_s[f + 5]);
      o.w = pack_bf16(blo(u.w) * scl_s[f + 6] + sht_s[f + 6], bhi(u.w) * scl_s[f + 7] + sht_s[f + 7]);
      *(uint4*)&Al[r * 136 + f] = o;
    }
  }
  __syncthreads();

  int m = lane & 31, half = lane >> 5;
  v8bf afrag[8];
#pragma unroll
  for (int s = 0; s < 8; ++s)
    afrag[s] = *(const v8bf*)&Al[m * 136 + s * 16 + half * 8];

  v16f acc0 = {}, acc1 = {};
#pragma unroll
  for (int s = 0; s < 8; ++s) {
    acc0 = __builtin_amdgcn_mfma_f32_32x32x16_bf16(afrag[s], bfrag[0][s], acc0, 0, 0, 0);
    acc1 = __builtin_amdgcn_mfma_f32_32x32x16_bf16(afrag[s], bfrag[1][s], acc1, 0, 0, 0);
  }

  v16f acc2 = {};
  if (w == 0) {
#pragma unroll
    for (int s = 0; s < 8; ++s) {
      v8bf besf = *(const v8bf*)&Bp[(size_t)((64 + s) * 64 + lane) * 8];
      acc2 = __builtin_amdgcn_mfma_f32_32x32x16_bf16(afrag[s], besf, acc2, 0, 0, 0);
    }
  }

  int mlo = half * 4;
  int t0 = 2 * w, t1 = 2 * w + 1;
#pragma unroll
  for (int r = 0; r < 16; ++r) {
    int row = (r & 3) + 8 * (r >> 2) + mlo;
    int node = rowBase + row;
    float a0 = acc0[r], a1 = acc1[r];
    float b0 = __shfl_xor(a0, 1, 64);
    float b1 = __shfl_xor(a1, 1, 64);
    if (node < N && !(lane & 1)) {
      if (t0 < 4) {
        hb[(size_t)node * 64 + (t0 * 16 + (m >> 1))] = pack_bf16(a0, b0);
        hb[(size_t)node * 64 + (t1 * 16 + (m >> 1))] = pack_bf16(a1, b1);
      } else {
        linp[(size_t)node * 64 + ((t0 - 4) * 16 + (m >> 1))] = pack_bf16(a0, b0);
        linp[(size_t)node * 64 + ((t1 - 4) * 16 + (m >> 1))] = pack_bf16(a1, b1);
      }
    }
    if (w == 0 && m < 4 && node < N) {
      float v = acc2[r];
      if (m < 2) es[2 * node + (m & 1)] = v;
      else       ed[2 * node + (m & 1)] = v;
    }
  }
}

// =================== kernels ===================

// K1: prep (Bp tiles 0-8, Wesed->tile8, layer-1 BN stats) UNION binA.
// blocks [0,34): weight prep; [34,1058): stats; [1058, 1058+nblk): binA.
__global__ __launch_bounds__(256) void k_prepA(
    const float* __restrict__ W1, const float* __restrict__ LW1,
    const float* __restrict__ W2, const float* __restrict__ LW2,
    const float* __restrict__ as1, const float* __restrict__ ad1,
    const float* __restrict__ as2, const float* __restrict__ ad2,
    const float* __restrict__ x, int N,
    unsigned short* __restrict__ Bp1, unsigned short* __restrict__ Bp2,
    float* __restrict__ stats1,
    const void* ei, int E, int M, int nb, int nblk, int* counts) {
  __shared__ __align__(16) int lds[1025];
  int blk = blockIdx.x;
  int tid = threadIdx.x;
  if (blk >= 1058) { binA_body(blk - 1058, ei, N, E, M, nb, nblk, counts, lds); return; }
  if (blk >= 34) {
    int b = blk - 34;  // 0..1023
    int f = tid & 127;
    int half = tid >> 7;
    float s = 0.f, s2 = 0.f;
    for (int r = b + half * 1024; r < N; r += 2048) {
      float v = x[(size_t)r * 128 + f];
      s += v; s2 += v * v;
    }
    float* rep = stats1 + (size_t)(b & 7) * 256;
    atomicAdd(&rep[f], s);
    atomicAdd(&rep[128 + f], s2);
    return;
  }
  if (blk >= 32) {
    // tile 8: es/ed columns in B-fragment order
    float (*wes)[4] = (float(*)[4])lds;  // 128x4 floats = 2 KB
    const float* W = (blk == 32) ? W1 : W2;
    const float* as_ = (blk == 32) ? as1 : as2;
    const float* ad_ = (blk == 32) ? ad1 : ad2;
    unsigned short* Bp = (blk == 32) ? Bp1 : Bp2;
#pragma unroll
    for (int it = 0; it < 2; ++it) {
      int k = tid & 127;
      int c = (tid >> 7) + 2 * it;
      const float* a = (c < 2) ? as_ : ad_;
      int hb2 = (c & 1) * 64;
      float sum = 0.f;
      for (int f = 0; f < 64; ++f) sum += W[k * 128 + hb2 + f] * a[hb2 + f];
      wes[k][c] = sum;
    }
    __syncthreads();
    for (int fr = tid; fr < 512; fr += 256) {
      int lane = fr & 63, s = fr >> 6;
      int n = lane & 31;
      int k0 = s * 16 + (lane >> 5) * 8;
      unsigned short tb[8];
#pragma unroll
      for (int j = 0; j < 8; ++j)
        tb[j] = bf16of((n < 4) ? wes[k0 + j][n] : 0.f);
      uint4 pk;
      pk.x = (unsigned)tb[0] | ((unsigned)tb[1] << 16);
      pk.y = (unsigned)tb[2] | ((unsigned)tb[3] << 16);
      pk.z = (unsigned)tb[4] | ((unsigned)tb[5] << 16);
      pk.w = (unsigned)tb[6] | ((unsigned)tb[7] << 16);
      int fi = (64 + s) * 64 + lane;
      *(uint4*)&Bp[(size_t)fi * 8] = pk;
    }
    return;
  }
  const float* W  = (blk < 16) ? W1 : W2;
  const float* LW = (blk < 16) ? LW1 : LW2;
  unsigned short* Bp = (blk < 16) ? Bp1 : Bp2;
  int fi = (blk & 15) * 256 + tid;  // 4096 frags (tiles 0-7)
  int lane = fi & 63, s = (fi >> 6) & 7, t = fi >> 9;
  int n = t * 32 + (lane & 31);
  int k0 = s * 16 + (lane >> 5) * 8;
  unsigned short tb[8];
#pragma unroll
  for (int j = 0; j < 8; ++j) {
    int k = k0 + j;
    float v = (n < 128) ? W[k * 128 + n] : LW[k * 128 + (n - 128)];
    tb[j] = bf16of(v);
  }
  uint4 pk;
  pk.x = (unsigned)tb[0] | ((unsigned)tb[1] << 16);
  pk.y = (unsigned)tb[2] | ((unsigned)tb[3] << 16);
  pk.z = (unsigned)tb[4] | ((unsigned)tb[5] << 16);
  pk.w = (unsigned)tb[6] | ((unsigned)tb[7] << 16);
  *(uint4*)&Bp[(size_t)fi * 8] = pk;
}

__global__ __launch_bounds__(1024) void k_binScan(int* counts, int total_entries) {
  __shared__ int part[1024];
  int tid = threadIdx.x;
  int per = (total_entries + 1023) / 1024;
  int lo = tid * per;
  int hi = lo + per; if (hi > total_entries) hi = total_entries;
  int s = 0;
  int i = lo;
  for (; i + 8 <= hi; i += 8) {
    int c0 = counts[i], c1 = counts[i + 1], c2 = counts[i + 2], c3 = counts[i + 3];
    int c4 = counts[i + 4], c5 = counts[i + 5], c6 = counts[i + 6], c7 = counts[i + 7];
    s += ((c0 + c1) + (c2 + c3)) + ((c4 + c5) + (c6 + c7));
  }
  for (; i < hi; ++i) s += counts[i];
  part[tid] = s;
  __syncthreads();
  for (int off = 1; off < 1024; off <<= 1) {
    int add = (tid >= off) ? part[tid - off] : 0;
    __syncthreads();
    part[tid] += add;
    __syncthreads();
  }
  int run = (tid == 0) ? 0 : part[tid - 1];
  i = lo;
  for (; i + 8 <= hi; i += 8) {
    int c0 = counts[i], c1 = counts[i + 1], c2 = counts[i + 2], c3 = counts[i + 3];
    int c4 = counts[i + 4], c5 = counts[i + 5], c6 = counts[i + 6], c7 = counts[i + 7];
    counts[i] = run; run += c0;
    counts[i + 1] = run; run += c1;
    counts[i + 2] = run; run += c2;
    counts[i + 3] = run; run += c3;
    counts[i + 4] = run; run += c4;
    counts[i + 5] = run; run += c5;
    counts[i + 6] = run; run += c6;
    counts[i + 7] = run; run += c7;
  }
  for (; i < hi; ++i) {
    int c = counts[i];
    counts[i] = run;
    run += c;
  }
}

// K3: layer-1 MFMA matmul UNION binC. blocks [0,gmm): mm; [gmm, gmm+nblk): binC.
__global__ __launch_bounds__(256) void k_mmC(
    const void* __restrict__ xin, int packed,
    const float* __restrict__ stats, const float* __restrict__ gamma, const float* __restrict__ beta,
    const unsigned short* __restrict__ Bp,
    unsigned* __restrict__ hb, unsigned* __restrict__ linp,
    float* __restrict__ es, float* __restrict__ ed, int N, int gmm,
    const void* ei, int E, int M, int nb, int nblk, const int* counts, unsigned* tmp) {
  __shared__ __align__(16) char smem[MM_SMEM];
  int blk = blockIdx.x;
  if (blk < gmm) {
    mm_body(blk, xin, packed, stats, gamma, beta, Bp, hb, linp, es, ed, N, smem);
  } else {
    binC_body(blk - gmm, ei, N, E, M, nb, nblk, counts, tmp, (int*)smem);
  }
}

// standalone mm (layer 2)
__global__ __launch_bounds__(256) void k_mm(
    const void* __restrict__ xin, int packed,
    const float* __restrict__ stats, const float* __restrict__ gamma, const float* __restrict__ beta,
    const unsigned short* __restrict__ Bp,
    unsigned* __restrict__ hb, unsigned* __restrict__ linp,
    float* __restrict__ es, float* __restrict__ ed, int N) {
  __shared__ __align__(16) char smem[MM_SMEM];
  mm_body(blockIdx.x, xin, packed, stats, gamma, beta, Bp, hb, linp, es, ed, N, smem);
}

// binD: per-bucket (128 dsts) counting sort -> rowptr + col.
__global__ __launch_bounds__(256) void k_binD(const unsigned* __restrict__ tmp,
                                              const int* __restrict__ counts,
                                              int nb, int nblk, int M, int N,
                                              int* __restrict__ rowptr, int* __restrict__ col) {
  __shared__ int scn[128];
  __shared__ int cur[128];
  int tid = threadIdx.x;
  int j = blockIdx.x;
  int base = counts[(size_t)j * nblk];
  int endv = (j + 1 < nb) ? counts[(size_t)(j + 1) * nblk] : M;
  int bc = endv - base;
  if (tid < 128) scn[tid] = 0;
  __syncthreads();
  for (int i = tid; i < bc; i += 256) atomicAdd(&scn[tmp[base + i] & 127], 1);
  __syncthreads();
  int v = (tid < 128) ? scn[tid] : 0;
  __syncthreads();
  for (int off = 1; off < 128; off <<= 1) {
    int add = (tid >= off && tid < 128) ? scn[tid - off] : 0;
    __syncthreads();
    if (tid < 128) scn[tid] += add;
    __syncthreads();
  }
  if (tid < 128) {
    int excl = scn[tid] - v;
    int d = (j << 7) + tid;
    if (d < N) rowptr[d] = base + excl;
    cur[tid] = base + excl;
  }
  __syncthreads();
  for (int i = tid; i < bc; i += 256) {
    unsigned w = tmp[base + i];
    int pos = atomicAdd(&cur[w & 127], 1);
    col[pos] = (int)(w >> 7);
  }
  if (j == nb - 1 && tid == 0) rowptr[N] = M;
}

// ---------- BatchNorm stats for packed-bf16 input (layers 2/3) ----------
__global__ __launch_bounds__(128) void k_bnstats(const unsigned* __restrict__ xp,
                                                 int N, float* sums) {
  int f = threadIdx.x;
  int q = f >> 1, hi = f & 1;
  float s = 0.f, s2 = 0.f;
  for (int r = blockIdx.x; r < N; r += gridDim.x) {
    unsigned u = xp[(size_t)r * 64 + q];
    float v = hi ? bhi(u) : blo(u);
    s += v; s2 += v * v;
  }
  float* rep = sums + (size_t)(blockIdx.x & 7) * 256;
  atomicAdd(&rep[f], s);
  atomicAdd(&rep[128 + f], s2);
}

// ---------- single-pass edge aggregation + combine; one wave per dst ----------
__global__ __launch_bounds__(256) void k_agg(
    const int* __restrict__ rowptr, const int* __restrict__ col,
    const float* __restrict__ es, const float* __restrict__ ed,
    const unsigned* __restrict__ hb, const unsigned* __restrict__ linp,
    const float* __restrict__ lb, const float* __restrict__ gb,
    unsigned* __restrict__ xoutp, int N) {
  int lane = threadIdx.x & 63;
  int w = threadIdx.x >> 6;
  int d = blockIdx.x * 4 + w;
  if (d >= N) return;
  int start = rowptr[d], end = rowptr[d + 1];
  v2f edv = *(const v2f*)&ed[2 * d];
  int q = lane >> 4;   // edge quarter 0..3
  int m = lane & 15;   // feats 8m..8m+7
  int head_hi = m >= 8;
  v2f zero = {0.f, 0.f};
  v2f lk = {LEAKY, LEAKY};

  v2f acc[4] = {zero, zero, zero, zero};
  v2f sp = zero;
  int i = start;
  for (; i + 16 <= end; i += 16) {
#pragma unroll
    for (int b = 0; b < 4; ++b) {
      int idx = i + 4 * b + q;
      int s = col[idx];
      v2f ev = *(const v2f*)&es[2 * s];
      uint4 u = *(const uint4*)&hb[(size_t)s * 64 + m * 4];
      v2f e = ev + edv;
      v2f le = __builtin_elementwise_max(e, zero) + lk * __builtin_elementwise_min(e, zero);
      v2f p; p.x = __expf(le.x); p.y = __expf(le.y);
      sp += p;
      float f = head_hi ? p.y : p.x;
      v2f fv = {f, f};
      acc[0] = __builtin_elementwise_fma(fv, bpair(u.x), acc[0]);
      acc[1] = __builtin_elementwise_fma(fv, bpair(u.y), acc[1]);
      acc[2] = __builtin_elementwise_fma(fv, bpair(u.z), acc[2]);
      acc[3] = __builtin_elementwise_fma(fv, bpair(u.w), acc[3]);
    }
  }
  for (; i < end; i += 4) {  // masked tail, 4 edges/iter
    int idx = i + q;
    int valid = idx < end;
    int s = col[valid ? idx : end - 1];
    v2f ev = *(const v2f*)&es[2 * s];
    uint4 u = *(const uint4*)&hb[(size_t)s * 64 + m * 4];
    v2f e = ev + edv;
    v2f le = __builtin_elementwise_max(e, zero) + lk * __builtin_elementwise_min(e, zero);
    v2f p; p.x = __expf(le.x); p.y = __expf(le.y);
    if (!valid) p = zero;
    sp += p;
    float f = head_hi ? p.y : p.x;
    v2f fv = {f, f};
    acc[0] = __builtin_elementwise_fma(fv, bpair(u.x), acc[0]);
    acc[1] = __builtin_elementwise_fma(fv, bpair(u.y), acc[1]);
    acc[2] = __builtin_elementwise_fma(fv, bpair(u.z), acc[2]);
    acc[3] = __builtin_elementwise_fma(fv, bpair(u.w), acc[3]);
  }
  // reduce across quarters
#pragma unroll
  for (int k = 0; k < 4; ++k) {
    acc[k].x += __shfl_xor(acc[k].x, 16, 64);
    acc[k].x += __shfl_xor(acc[k].x, 32, 64);
    acc[k].y += __shfl_xor(acc[k].y, 16, 64);
    acc[k].y += __shfl_xor(acc[k].y, 32, 64);
  }
  sp.x += __shfl_xor(sp.x, 16, 64); sp.x += __shfl_xor(sp.x, 32, 64);
  sp.y += __shfl_xor(sp.y, 16, 64); sp.y += __shfl_xor(sp.y, 32, 64);

  if (q == 0) {
    float inv = 1.0f / (head_hi ? sp.y : sp.x);
    uint4 lv = *(const uint4*)&linp[(size_t)d * 64 + m * 4];
    int f8 = 8 * m;
    float4 lb0 = *(const float4*)&lb[f8], lb1 = *(const float4*)&lb[f8 + 4];
    float4 gb0 = *(const float4*)&gb[f8], gb1 = *(const float4*)&gb[f8 + 4];
    float v0 = blo(lv.x) + lb0.x + acc[0].x * inv + gb0.x;
    float v1 = bhi(lv.x) + lb0.y + acc[0].y * inv + gb0.y;
    float v2 = blo(lv.y) + lb0.z + acc[1].x * inv + gb0.z;
    float v3 = bhi(lv.y) + lb0.w + acc[1].y * inv + gb0.w;
    float v4 = blo(lv.z) + lb1.x + acc[2].x * inv + gb1.x;
    float v5 = bhi(lv.z) + lb1.y + acc[2].y * inv + gb1.y;
    float v6 = blo(lv.w) + lb1.z + acc[3].x * inv + gb1.z;
    float v7 = bhi(lv.w) + lb1.w + acc[3].y * inv + gb1.w;
    v0 = v0 > 0.f ? v0 : 0.f; v1 = v1 > 0.f ? v1 : 0.f;
    v2 = v2 > 0.f ? v2 : 0.f; v3 = v3 > 0.f ? v3 : 0.f;
    v4 = v4 > 0.f ? v4 : 0.f; v5 = v5 > 0.f ? v5 : 0.f;
    v6 = v6 > 0.f ? v6 : 0.f; v7 = v7 > 0.f ? v7 : 0.f;
    uint4 o;
    o.x = pack_bf16(v0, v1); o.y = pack_bf16(v2, v3);
    o.z = pack_bf16(v4, v5); o.w = pack_bf16(v6, v7);
    *(uint4*)&xoutp[(size_t)d * 64 + m * 4] = o;
  }
}

// ---------- layer 3: BN(inline, 8-replica stats) + tiny matmul + es/ed ----------
__global__ __launch_bounds__(256) void k_l3node(
    const unsigned* __restrict__ xp,
    const float* __restrict__ stats, const float* __restrict__ gamma, const float* __restrict__ beta,
    const float* __restrict__ W3, const float* __restrict__ LW3,
    const float* __restrict__ as3, const float* __restrict__ ad3,
    float* h3, float* lin3, float* es3, float* ed3, int N) {
  int lane = threadIdx.x & 63;
  int n = blockIdx.x * 4 + (threadIdx.x >> 6);
  if (n >= N) return;
  float inv_n = 1.0f / (float)N;
  int f0 = lane, f1 = 64 + lane;
  float su0 = 0.f, sq0 = 0.f, su1 = 0.f, sq1 = 0.f;
#pragma unroll
  for (int r = 0; r < 8; ++r) {
    su0 += stats[r * 256 + f0];  sq0 += stats[r * 256 + 128 + f0];
    su1 += stats[r * 256 + f1];  sq1 += stats[r * 256 + 128 + f1];
  }
  float mu0 = su0 * inv_n;
  float var0 = sq0 * inv_n - mu0 * mu0;
  float rs0 = rsqrtf(var0 + BN_EPS);
  float sc0 = gamma[f0] * rs0, sh0 = beta[f0] - mu0 * sc0;
  float mu1 = su1 * inv_n;
  float var1 = sq1 * inv_n - mu1 * mu1;
  float rs1 = rsqrtf(var1 + BN_EPS);
  float sc1 = gamma[f1] * rs1, sh1 = beta[f1] - mu1 * sc1;

  unsigned ua = xp[(size_t)n * 64 + (lane >> 1)];
  unsigned ub = xp[(size_t)n * 64 + 32 + (lane >> 1)];
  float xv0 = (lane & 1) ? bhi(ua) : blo(ua);
  float xv1 = (lane & 1) ? bhi(ub) : blo(ub);
  float xn0 = xv0 * sc0 + sh0;
  float xn1 = xv1 * sc1 + sh1;

  float2 w0 = *(const float2*)&W3[lane * 2];
  float2 w1 = *(const float2*)&W3[(64 + lane) * 2];
  float2 l0 = *(const float2*)&LW3[lane * 2];
  float2 l1 = *(const float2*)&LW3[(64 + lane) * 2];
  float hc0 = wsum(xn0 * w0.x + xn1 * w1.x);
  float hc1 = wsum(xn0 * w0.y + xn1 * w1.y);
  float lc0 = wsum(xn0 * l0.x + xn1 * l1.x);
  float lc1 = wsum(xn0 * l0.y + xn1 * l1.y);
  if (lane == 0) {
    h3[2 * n] = hc0; h3[2 * n + 1] = hc1;
    lin3[2 * n] = lc0; lin3[2 * n + 1] = lc1;
    es3[n] = hc0 * as3[0] + hc1 * as3[1];
    ed3[n] = hc0 * ad3[0] + hc1 * ad3[1];
  }
}

// ---------- layer 3 edge aggregation + final output ----------
__global__ __launch_bounds__(256) void k_agg3(
    const int* __restrict__ rowptr, const int* __restrict__ col,
    const float* __restrict__ es, const float* __restrict__ ed,
    const float* __restrict__ h3, const float* __restrict__ lin3,
    const float* __restrict__ lb3, const float* __restrict__ gb3,
    float* __restrict__ out, int N) {
  int lane = threadIdx.x & 63;
  int d = blockIdx.x * 4 + (threadIdx.x >> 6);
  if (d >= N) return;
  int start = rowptr[d], end = rowptr[d + 1];
  float edd = ed[d];
  float ps = 0.f, a0 = 0.f, a1 = 0.f;
  for (int i = start + lane; i < end; i += 64) {
    int s = col[i];
    float e = es[s] + edd; e = e > 0.f ? e : LEAKY * e;
    float p = __expf(e);
    float2 hv = *(const float2*)&h3[2 * s];
    ps += p; a0 += p * hv.x; a1 += p * hv.y;
  }
  ps = wsum(ps); a0 = wsum(a0); a1 = wsum(a1);
  if (lane < 2) {
    float a = (lane == 0 ? a0 : a1) / ps;
    float v = lin3[2 * d + lane] + lb3[lane] + a + gb3[lane];
    out[2 * d + lane] = v > 0.f ? v : 0.f;
  }
}

extern "C" void kernel_launch(void* const* d_in, const int* in_sizes, int n_in,
                              void* d_out, int out_size, void* d_ws, size_t ws_size,
                              hipStream_t stream) {
  const float* x   = (const float*)d_in[0];
  const void*  ei  = d_in[1];
  const float* W1  = (const float*)d_in[2];
  const float* as1 = (const float*)d_in[3];
  const float* ad1 = (const float*)d_in[4];
  const float* gb1 = (const float*)d_in[5];
  const float* lw1 = (const float*)d_in[6];
  const float* lb1 = (const float*)d_in[7];
  const float* bg1 = (const float*)d_in[8];
  const float* bb1 = (const float*)d_in[9];
  const float* W2  = (const float*)d_in[10];
  const float* as2 = (const float*)d_in[11];
  const float* ad2 = (const float*)d_in[12];
  const float* gb2 = (const float*)d_in[13];
  const float* lw2 = (const float*)d_in[14];
  const float* lb2 = (const float*)d_in[15];
  const float* bg2 = (const float*)d_in[16];
  const float* bb2 = (const float*)d_in[17];
  const float* W3  = (const float*)d_in[18];
  const float* as3 = (const float*)d_in[19];
  const float* ad3 = (const float*)d_in[20];
  const float* gb3 = (const float*)d_in[21];
  const float* lw3 = (const float*)d_in[22];
  const float* lb3 = (const float*)d_in[23];
  const float* bg3 = (const float*)d_in[24];
  const float* bb3 = (const float*)d_in[25];
  float* out = (float*)d_out;

  int N = in_sizes[0] / 128;
  int E = in_sizes[1] / 2;
  int M = E + N;
  int nb = (N + 127) >> 7;            // 128-wide buckets
  int nblk = (M + BCHUNK - 1) / BCHUNK;

  char* wsp = (char*)d_ws;
  size_t off = 0;
  auto alloc = [&](size_t bytes) -> void* {
    void* p = wsp + off;
    off = (off + bytes + 255) & ~(size_t)255;
    return p;
  };
  int* rowptr   = (int*)alloc(((size_t)N + 1) * 4);
  int* col      = (int*)alloc((size_t)M * 4);
  unsigned* tmp = (unsigned*)alloc((size_t)M * 4);
  int* counts   = (int*)alloc(((size_t)nb * nblk + 1) * 4);
  float* st1    = (float*)alloc(8 * 256 * 4);
  float* st2    = (float*)alloc(8 * 256 * 4);
  float* st3    = (float*)alloc(8 * 256 * 4);
  unsigned short* Bp1 = (unsigned short*)alloc(4608 * 16);  // 9 tiles
  unsigned short* Bp2 = (unsigned short*)alloc(4608 * 16);
  unsigned* hbp  = (unsigned*)alloc((size_t)N * 64 * 4);
  unsigned* linp = (unsigned*)alloc((size_t)N * 64 * 4);
  unsigned* x2p  = (unsigned*)alloc((size_t)N * 64 * 4);
  float* es    = (float*)alloc((size_t)N * 2 * 4);
  float* edb   = (float*)alloc((size_t)N * 2 * 4);
  float* h3    = (float*)alloc((size_t)N * 2 * 4);
  float* lin3  = (float*)alloc((size_t)N * 2 * 4);
  float* es3   = (float*)alloc((size_t)N * 4);
  float* ed3   = (float*)alloc((size_t)N * 4);
  (void)ws_size; (void)n_in; (void)out_size;

  hipMemsetAsync(st1, 0, 3 * 8 * 256 * 4, stream);  // st1,st2,st3 contiguous

  int gnode = (N + 3) / 4;
  int gmm = (N + 31) / 32;

  // K1: weight prep + layer-1 BN stats + binA (merged, independent work)
  k_prepA<<<1058 + nblk, 256, 0, stream>>>(W1, lw1, W2, lw2, as1, ad1, as2, ad2,
                                           x, N, Bp1, Bp2, st1,
                                           ei, E, M, nb, nblk, counts);
  k_binScan<<<1, 1024, 0, stream>>>(counts, nb * nblk);
  // K3: layer-1 matmul + binC (merged, independent work)
  k_mmC<<<gmm + nblk, 256, 0, stream>>>(x, 0, st1, bg1, bb1, Bp1, hbp, linp, es, edb, N,
                                        gmm, ei, E, M, nb, nblk, counts, tmp);
  k_binD<<<nb, 256, 0, stream>>>(tmp, counts, nb, nblk, M, N, rowptr, col);

  // ---- layer 1 aggregation ----
  k_agg<<<gnode, 256, 0, stream>>>(rowptr, col, es, edb, hbp, linp, lb1, gb1, x2p, N);

  // ---- layer 2 ----
  k_bnstats<<<1024, 128, 0, stream>>>(x2p, N, st2);
  k_mm<<<gmm, 256, 0, stream>>>(x2p, 1, st2, bg2, bb2, Bp2, hbp, linp, es, edb, N);
  k_agg<<<gnode, 256, 0, stream>>>(rowptr, col, es, edb, hbp, linp, lb2, gb2, x2p, N);

  // ---- layer 3 ----
  k_bnstats<<<1024, 128, 0, stream>>>(x2p, N, st3);
  k_l3node<<<gnode, 256, 0, stream>>>(x2p, st3, bg3, bb3, W3, lw3, as3, ad3,
                                      h3, lin3, es3, ed3, N);
  k_agg3<<<gnode, 256, 0, stream>>>(rowptr, col, es3, ed3, h3, lin3, lb3, gb3, out, N);
}